// Round 16
// baseline (424.201 us; speedup 1.0000x reference)
//
#include <hip/hip_runtime.h>
#include <hip/hip_bf16.h>

#define B_ 16
#define T_ 32
#define D_ 4096
#define H_ 32
#define HD_ 128
#define MAXS_ 2048
#define M_ (B_*T_)   // 512 rows

typedef __hip_bfloat16 bf16;
typedef __attribute__((ext_vector_type(8))) short bf16x8;
typedef __attribute__((ext_vector_type(4))) float f32x4;

static __device__ __forceinline__ short f2b(float f) {
    bf16 h = __float2bfloat16(f);
    return *reinterpret_cast<short*>(&h);
}
static __device__ __forceinline__ float b2f(short s) {
    bf16 h;
    *reinterpret_cast<short*>(&h) = s;
    return __bfloat162float(h);
}

// async global->LDS, 16B per lane; LDS dest is wave-uniform base + lane*16
#define GLD16(gsrc, ldst) \
    __builtin_amdgcn_global_load_lds((const __attribute__((address_space(1))) void*)(gsrc), \
        (__attribute__((address_space(3))) void*)(ldst), 16, 0, 0)

// ---------------- x f32 -> bf16 ----------------
__global__ __launch_bounds__(256) void conv_x(const float* __restrict__ x, bf16* __restrict__ xb) {
    int idx = blockIdx.x * 256 + threadIdx.x;   // 8-element unit
    const float4* xf = (const float4*)x;
    float4 a = xf[idx * 2], b = xf[idx * 2 + 1];
    bf16x8 o;
    o[0] = f2b(a.x); o[1] = f2b(a.y); o[2] = f2b(a.z); o[3] = f2b(a.w);
    o[4] = f2b(b.x); o[5] = f2b(b.y); o[6] = f2b(b.z); o[7] = f2b(b.w);
    *(bf16x8*)&xb[(size_t)idx * 8] = o;
}

// ---------------- single W [k][n] f32 -> Wt [n][k] bf16 (wo only) ----------------
__global__ __launch_bounds__(256) void transpose_w(const float* __restrict__ W, bf16* __restrict__ wt) {
    __shared__ float Ts[64][65];
    const int n0 = blockIdx.x * 64, k0 = blockIdx.y * 64;
    const int t = threadIdx.x;
    {
        int kk = t >> 4, nn = (t & 15) * 4;
        #pragma unroll
        for (int r = 0; r < 4; ++r) {
            float4 v = *(const float4*)&W[(size_t)(k0 + kk + 16 * r) * D_ + n0 + nn];
            Ts[kk + 16 * r][nn + 0] = v.x;
            Ts[kk + 16 * r][nn + 1] = v.y;
            Ts[kk + 16 * r][nn + 2] = v.z;
            Ts[kk + 16 * r][nn + 3] = v.w;
        }
    }
    __syncthreads();
    const int kg = t & 7, nr = t >> 3;
    #pragma unroll
    for (int r = 0; r < 2; ++r) {
        int n = nr + 32 * r;
        bf16x8 o;
        #pragma unroll
        for (int j = 0; j < 8; ++j) o[j] = f2b(Ts[kg * 8 + j][n]);
        *(bf16x8*)&wt[(size_t)(n0 + n) * D_ + k0 + kg * 8] = o;
    }
}

// ---------------- QKV GEMM: reg-staged, software-pipelined one K-step ahead ----------------
// No global_load_lds => __syncthreads only drains lgkmcnt; prefetch loads (plain VGPR
// loads) stay in flight across the barrier and are consumed one full K-step later.
// BM=64, BN=128, BK=64, grid (96, 8): blockIdx.x>>5 selects wq/wk/wv.
__global__ __launch_bounds__(256) void gemm_qkvw(const bf16* __restrict__ A,
        const float* __restrict__ wq, const float* __restrict__ wk,
        const float* __restrict__ wv, bf16* __restrict__ out) {
    const int K = D_;
    const int wsel = blockIdx.x >> 5;
    const float* W = (wsel == 0) ? wq : (wsel == 1) ? wk : wv;
    const int lcol0 = (blockIdx.x & 31) * 128;
    bf16* Ob = out + (size_t)wsel * M_ * D_;
    __shared__ bf16 As[2][64 * 32];      // two 32-k halves, swizzled layout
    __shared__ short Bs[2][128][40];     // 80B stride + xor
    const int tid = threadIdx.x, lane = tid & 63, wave = tid >> 6;
    const int wr = wave >> 1, wc = wave & 1;
    const int lg = lane >> 4, li = lane & 15;
    const int row0 = blockIdx.y * 64;
    const int bq = tid & 31, kq = tid >> 5;
    f32x4 acc[2][4];
    #pragma unroll
    for (int i = 0; i < 2; ++i)
        #pragma unroll
        for (int j = 0; j < 4; ++j)
            #pragma unroll
            for (int r = 0; r < 4; ++r) acc[i][j][r] = 0.f;

    const int sw = (li & 3) << 4;
    // A: same bytes/layout as the old gload_lds path, via regs
    const int Arow = tid >> 2;
    const int Akb = ((tid * 16) & 63) ^ ((Arow & 3) << 4);
    const char* Abase = (const char*)(A + (size_t)(row0 + Arow) * K) + Akb;

    auto WLOAD = [&](int k0, float4 (&wvv)[2][4]) {
        #pragma unroll
        for (int h = 0; h < 2; ++h)
            #pragma unroll
            for (int i = 0; i < 4; ++i)
                wvv[h][i] = *(const float4*)&W[(size_t)(k0 + 32 * h + kq * 4 + i) * D_ + lcol0 + bq * 4];
    };
    auto ALOAD = [&](int k0, uint4 (&avv)[2]) {
        avv[0] = *(const uint4*)(Abase + (size_t)k0 * 2);
        avv[1] = *(const uint4*)(Abase + (size_t)k0 * 2 + 64);
    };
    auto STAGE = [&](float4 (&wvv)[2][4], uint4 (&avv)[2]) {
        *(uint4*)((char*)As[0] + tid * 16) = avv[0];
        *(uint4*)((char*)As[1] + tid * 16) = avv[1];
        #pragma unroll
        for (int h = 0; h < 2; ++h)
            #pragma unroll
            for (int j = 0; j < 4; ++j) {
                int n = bq * 4 + j;
                short4 col;
                col.x = f2b(((const float*)&wvv[h][0])[j]);
                col.y = f2b(((const float*)&wvv[h][1])[j]);
                col.z = f2b(((const float*)&wvv[h][2])[j]);
                col.w = f2b(((const float*)&wvv[h][3])[j]);
                *(short4*)((char*)&Bs[h][n][0] + ((kq * 8) ^ (((n >> 4) & 3) << 4))) = col;
            }
    };
    auto STEP = [&]() {
        bf16x8 af[2][2], bfr[2][4];
        #pragma unroll
        for (int h = 0; h < 2; ++h) {
            #pragma unroll
            for (int i = 0; i < 2; ++i) {
                int row = wr * 32 + i * 16 + li;
                af[h][i] = *(const bf16x8*)((const char*)As[h] + row * 64 + ((lg * 16) ^ sw));
            }
            #pragma unroll
            for (int j = 0; j < 4; ++j) {
                int row = wc * 64 + j * 16 + li;
                bfr[h][j] = *(const bf16x8*)((const char*)&Bs[h][row][0] + ((lg * 16) ^ (((row >> 4) & 3) << 4)));
            }
        }
        #pragma unroll
        for (int h = 0; h < 2; ++h)
            #pragma unroll
            for (int i = 0; i < 2; ++i)
                #pragma unroll
                for (int j = 0; j < 4; ++j)
                    acc[i][j] = __builtin_amdgcn_mfma_f32_16x16x32_bf16(af[h][i], bfr[h][j], acc[i][j], 0, 0, 0);
    };

    float4 wA[2][4], wB[2][4];
    uint4 aA[2], aB[2];
    WLOAD(0, wA);
    ALOAD(0, aA);
    for (int k0 = 0; k0 < K; k0 += 128) {
        STAGE(wA, aA);                       // consume prefetch (waits on wA/aA here)
        WLOAD(k0 + 64, wB);                  // next-step loads: in flight across barrier+MFMA
        ALOAD(k0 + 64, aB);
        __syncthreads();
        STEP();
        __syncthreads();
        STAGE(wB, aB);
        if (k0 + 128 < K) {
            WLOAD(k0 + 128, wA);
            ALOAD(k0 + 128, aA);
        }
        __syncthreads();
        STEP();
        __syncthreads();
    }
    #pragma unroll
    for (int i = 0; i < 2; ++i)
        for (int j = 0; j < 4; ++j)
            for (int r = 0; r < 4; ++r) {
                int row = row0 + wr * 32 + i * 16 + lg * 4 + r;
                int col = lcol0 + wc * 64 + j * 16 + li;
                Ob[(size_t)row * D_ + col] = __float2bfloat16(acc[i][j][r]);
            }
}

// ---------------- bf16 GEMM (pre-transposed Bt), BK=64 via 2x 32-k halves — used for wo ----------------
template<int BM, int BN>
__global__ __launch_bounds__(256) void gemm_bf16t(const bf16* __restrict__ A,
        const bf16* __restrict__ Bt, float* __restrict__ O) {
    constexpr int IM = BM / 32;
    constexpr int JN = BN / 32;
    constexpr int nA = (BM * 64) / 4096;
    constexpr int nB = (BN * 64) / 4096;
    const int K = D_;
    __shared__ bf16 As[2][BM * 32];
    __shared__ bf16 Bs[2][BN * 32];
    const int tid = threadIdx.x, lane = tid & 63, wave = tid >> 6;
    const int wr = wave >> 1, wc = wave & 1;
    const int lg = lane >> 4, li = lane & 15;
    const int row0 = blockIdx.y * BM, col0 = blockIdx.x * BN;
    f32x4 acc[IM][JN];
    #pragma unroll
    for (int i = 0; i < IM; ++i)
        #pragma unroll
        for (int j = 0; j < JN; ++j)
            #pragma unroll
            for (int r = 0; r < 4; ++r) acc[i][j][r] = 0.f;

    const int sw = (li & 3) << 4;
    for (int k0 = 0; k0 < K; k0 += 64) {
        #pragma unroll
        for (int h = 0; h < 2; ++h) {
            #pragma unroll
            for (int i = 0; i < nA; ++i) {
                int X = (i * 256 + tid) * 16;
                int row = X >> 6;
                int kb = (X & 63) ^ ((row & 3) << 4);
                GLD16(A + (size_t)(row0 + row) * K + k0 + 32 * h + (kb >> 1),
                      (char*)As[h] + (i * 256 + wave * 64) * 16);
            }
            #pragma unroll
            for (int i = 0; i < nB; ++i) {
                int X = (i * 256 + tid) * 16;
                int row = X >> 6;
                int kb = (X & 63) ^ ((row & 3) << 4);
                GLD16(Bt + (size_t)(col0 + row) * K + k0 + 32 * h + (kb >> 1),
                      (char*)Bs[h] + (i * 256 + wave * 64) * 16);
            }
        }
        __syncthreads();
        bf16x8 af[2][IM], bfr[2][JN];
        #pragma unroll
        for (int h = 0; h < 2; ++h) {
            #pragma unroll
            for (int i = 0; i < IM; ++i) {
                int row = wr * (BM / 2) + i * 16 + li;
                af[h][i] = *(const bf16x8*)((const char*)As[h] + row * 64 + ((lg * 16) ^ sw));
            }
            #pragma unroll
            for (int j = 0; j < JN; ++j) {
                int row = wc * (BN / 2) + j * 16 + li;
                bfr[h][j] = *(const bf16x8*)((const char*)Bs[h] + row * 64 + ((lg * 16) ^ sw));
            }
        }
        #pragma unroll
        for (int h = 0; h < 2; ++h)
            #pragma unroll
            for (int i = 0; i < IM; ++i)
                #pragma unroll
                for (int j = 0; j < JN; ++j)
                    acc[i][j] = __builtin_amdgcn_mfma_f32_16x16x32_bf16(af[h][i], bfr[h][j], acc[i][j], 0, 0, 0);
        __syncthreads();
    }
    #pragma unroll
    for (int i = 0; i < IM; ++i)
        for (int j = 0; j < JN; ++j)
            for (int r = 0; r < 4; ++r) {
                int row = row0 + wr * (BM / 2) + i * 16 + lg * 4 + r;
                int col = col0 + wc * (BN / 2) + j * 16 + li;
                O[(size_t)row * D_ + col] = acc[i][j][r];
            }
}

// ---------------- RoPE in-place on bf16 q,k ----------------
__global__ __launch_bounds__(256) void rope_inplace(bf16* __restrict__ qb, bf16* __restrict__ kb) {
    int idx = blockIdx.x * 256 + threadIdx.x;
    size_t e0 = (size_t)idx * 8;
    int hd0 = (int)(e0 & 127);
    int t = (int)((e0 >> 12) & 31);
    bf16x8 q = *(bf16x8*)&qb[e0];
    bf16x8 k = *(bf16x8*)&kb[e0];
    bf16x8 qo, ko;
    #pragma unroll
    for (int p = 0; p < 4; ++p) {
        int i = (hd0 >> 1) + p;
        float theta = exp2f(-(float)i * 0.41524101186092787f);  // log2(10000)/32
        float s, c;
        sincosf((float)t * theta, &s, &c);
        float q0 = b2f(q[2 * p]), q1 = b2f(q[2 * p + 1]);
        qo[2 * p]     = f2b(q0 * c - q1 * s);
        qo[2 * p + 1] = f2b(q1 * c + q0 * s);
        float k0 = b2f(k[2 * p]), k1 = b2f(k[2 * p + 1]);
        ko[2 * p]     = f2b(k0 * c - k1 * s);
        ko[2 * p + 1] = f2b(k1 * c + k0 * s);
    }
    *(bf16x8*)&qb[e0] = qo;
    *(bf16x8*)&kb[e0] = ko;
}

// ---------------- Fused flash attention: deep async staging (gload_lds V + reg-prefetch K) ----------------
__global__ __launch_bounds__(256, 2) void attn(const bf16* __restrict__ qb,
        const bf16* __restrict__ kb, const bf16* __restrict__ vb,
        const float* __restrict__ kc, const float* __restrict__ vc,
        const int* __restrict__ spp, bf16* __restrict__ ob) {
    const int bh = blockIdx.x;
    const int b = bh >> 5, h = bh & 31;
    const int sp = *spp;
    const int L = sp + T_;
    const int tid = threadIdx.x, lane = tid & 63, wave = tid >> 6;
    const int lg = lane >> 4, li = lane & 15;

    __shared__ __align__(16) char smem[76928];
    char* VLDSw = smem + wave * 16384;
    float(*Vf)[128] = (float(*)[128])VLDSw;
    auto Plds = (bf16(*)[32][40])(smem + 65536);
    auto msh  = (float(*)[32])(smem + 75776);
    auto lsh  = (float(*)[32])(smem + 76288);
    float* ltot = (float*)(smem + 76800);
    float(*Osh)[128] = (float(*)[128])smem;            // post-loop overlay

    bf16x8 qf[2][4];
    #pragma unroll
    for (int rt = 0; rt < 2; ++rt)
        #pragma unroll
        for (int kk = 0; kk < 4; ++kk)
            qf[rt][kk] = *(const bf16x8*)(&qb[((size_t)(b * T_ + rt * 16 + li) * H_ + h) * HD_ + kk * 32 + lg * 8]);

    f32x4 o[2][8];
    float m_r[2], l_r[2];
    m_r[0] = m_r[1] = -1e30f;
    l_r[0] = l_r[1] = 0.f;
    #pragma unroll
    for (int rt = 0; rt < 2; ++rt) for (int ht = 0; ht < 8; ++ht) for (int r = 0; r < 4; ++r) o[rt][ht][r] = 0.f;

    const float scale = 0.08838834764831845f;  // 1/sqrt(128)
    const int nch = (L + 31) >> 5;
    const int ccache = sp >> 5;

    bf16x8 kf[2][4];
    float4 kr[16];

    auto KISSUE = [&](int cc) {
        #pragma unroll
        for (int ct = 0; ct < 2; ++ct) {
            const float* kp = &kc[(((size_t)b * MAXS_ + cc * 32 + ct * 16 + li) * H_ + h) * HD_ + lg * 8];
            #pragma unroll
            for (int kk = 0; kk < 4; ++kk) {
                kr[ct * 8 + 2 * kk]     = *(const float4*)(kp + kk * 32);
                kr[ct * 8 + 2 * kk + 1] = *(const float4*)(kp + kk * 32 + 4);
            }
        }
    };
    auto VSTAGE = [&](int cc) {
        const float* src = vc + (((size_t)b * MAXS_ + cc * 32) * H_ + h) * HD_;
        #pragma unroll
        for (int i = 0; i < 16; ++i) {
            GLD16(src + (size_t)(2 * i + (lane >> 5)) * (H_ * HD_) + (lane & 31) * 4,
                  VLDSw + i * 1024);
        }
    };
    auto KBUILD = [&]() {
        #pragma unroll
        for (int ct = 0; ct < 2; ++ct)
            #pragma unroll
            for (int kk = 0; kk < 4; ++kk) {
                bf16x8 f;
                f[0] = f2b(kr[ct * 8 + 2 * kk].x); f[1] = f2b(kr[ct * 8 + 2 * kk].y);
                f[2] = f2b(kr[ct * 8 + 2 * kk].z); f[3] = f2b(kr[ct * 8 + 2 * kk].w);
                f[4] = f2b(kr[ct * 8 + 2 * kk + 1].x); f[5] = f2b(kr[ct * 8 + 2 * kk + 1].y);
                f[6] = f2b(kr[ct * 8 + 2 * kk + 1].z); f[7] = f2b(kr[ct * 8 + 2 * kk + 1].w);
                kf[ct][kk] = f;
            }
    };

    auto COMPUTE = [&](int s0, bool deep) {
        f32x4 sc[2][2];
        #pragma unroll
        for (int ct = 0; ct < 2; ++ct)
            #pragma unroll
            for (int rt = 0; rt < 2; ++rt) {
                f32x4 acc;
                for (int r = 0; r < 4; ++r) acc[r] = 0.f;
                #pragma unroll
                for (int kk = 0; kk < 4; ++kk)
                    acc = __builtin_amdgcn_mfma_f32_16x16x32_bf16(kf[ct][kk], qf[rt][kk], acc, 0, 0, 0);
                sc[ct][rt] = acc;
            }
        float corr[2];
        #pragma unroll
        for (int rt = 0; rt < 2; ++rt) {
            float xv[8];
            #pragma unroll
            for (int ct = 0; ct < 2; ++ct)
                #pragma unroll
                for (int r = 0; r < 4; ++r) {
                    float xx = sc[ct][rt][r] * scale;
                    if (s0 + ct * 16 + 4 * lg + r >= L) xx = -1e30f;
                    xv[ct * 4 + r] = xx;
                }
            float mx = fmaxf(fmaxf(fmaxf(xv[0], xv[1]), fmaxf(xv[2], xv[3])),
                             fmaxf(fmaxf(xv[4], xv[5]), fmaxf(xv[6], xv[7])));
            mx = fmaxf(mx, __shfl_xor(mx, 16, 64));
            mx = fmaxf(mx, __shfl_xor(mx, 32, 64));
            float mnew = fmaxf(m_r[rt], mx);
            corr[rt] = __expf(m_r[rt] - mnew);
            float p[8], ssum = 0.f;
            #pragma unroll
            for (int j = 0; j < 8; ++j) { p[j] = __expf(xv[j] - mnew); ssum += p[j]; }
            ssum += __shfl_xor(ssum, 16, 64);
            ssum += __shfl_xor(ssum, 32, 64);
            l_r[rt] = l_r[rt] * corr[rt] + ssum;
            m_r[rt] = mnew;
            #pragma unroll
            for (int ct = 0; ct < 2; ++ct)
                #pragma unroll
                for (int r = 0; r < 4; ++r)
                    Plds[wave][rt * 16 + li][ct * 16 + 4 * lg + r] = __float2bfloat16(p[ct * 4 + r]);
        }
        #pragma unroll
        for (int rt = 0; rt < 2; ++rt) {
            float cq[4];
            #pragma unroll
            for (int r = 0; r < 4; ++r) cq[r] = __shfl(corr[rt], 20 * lg + r, 64);
            #pragma unroll
            for (int ht = 0; ht < 8; ++ht)
                #pragma unroll
                for (int r = 0; r < 4; ++r) o[rt][ht][r] *= cq[r];
        }
        if (deep) asm volatile("s_waitcnt vmcnt(16) lgkmcnt(0)" ::: "memory");
        else      asm volatile("s_waitcnt vmcnt(0) lgkmcnt(0)" ::: "memory");
        __builtin_amdgcn_sched_barrier(0);
        bf16x8 pf[2];
        pf[0] = *(const bf16x8*)(&Plds[wave][li][lg * 8]);
        pf[1] = *(const bf16x8*)(&Plds[wave][16 + li][lg * 8]);
        #pragma unroll
        for (int ht = 0; ht < 8; ++ht) {
            bf16x8 vf;
            #pragma unroll
            for (int j = 0; j < 8; ++j)
                vf[j] = f2b(Vf[lg * 8 + j][ht * 16 + li]);
            #pragma unroll
            for (int rt = 0; rt < 2; ++rt)
                o[rt][ht] = __builtin_amdgcn_mfma_f32_16x16x32_bf16(pf[rt], vf, o[rt][ht], 0, 0, 0);
        }
    };

    int c = wave;
    if (c < ccache) {
        KISSUE(c);
        VSTAGE(c);
        for (;;) {
            const int s0 = c * 32;
            const int nc = c + 4;
            const bool more = nc < ccache;
            KBUILD();
            if (more) KISSUE(nc);
            COMPUTE(s0, more);
            asm volatile("s_waitcnt lgkmcnt(0)" ::: "memory");
            if (more) VSTAGE(nc);
            c = nc;
            if (!more) break;
        }
    }
    for (; c < nch; c += 4) {
        const int s0 = c * 32;
        #pragma unroll
        for (int u = 0; u < 16; ++u) {
            int F = lane + 64 * u;
            int s = F >> 5, q = F & 31;
            int ss = s0 + s;
            float4 v;
            if (ss < sp) {
                v = *(const float4*)&vc[(((size_t)b * MAXS_ + ss) * H_ + h) * HD_ + q * 4];
            } else if (ss < L) {
                ushort4 uu = *(const ushort4*)&vb[(((size_t)b * T_ + (ss - sp)) * H_ + h) * HD_ + q * 4];
                v = make_float4(b2f((short)uu.x), b2f((short)uu.y), b2f((short)uu.z), b2f((short)uu.w));
            } else {
                v = make_float4(0.f, 0.f, 0.f, 0.f);
            }
            *(float4*)&Vf[s][q * 4] = v;
        }
        #pragma unroll
        for (int ct = 0; ct < 2; ++ct) {
            int s = s0 + ct * 16 + li;
            if (s < sp) {
                const float* kp = &kc[(((size_t)b * MAXS_ + s) * H_ + h) * HD_];
                #pragma unroll
                for (int kk = 0; kk < 4; ++kk) {
                    float4 v0 = *(const float4*)(&kp[kk * 32 + lg * 8]);
                    float4 v1 = *(const float4*)(&kp[kk * 32 + lg * 8 + 4]);
                    bf16x8 f;
                    f[0] = f2b(v0.x); f[1] = f2b(v0.y); f[2] = f2b(v0.z); f[3] = f2b(v0.w);
                    f[4] = f2b(v1.x); f[5] = f2b(v1.y); f[6] = f2b(v1.z); f[7] = f2b(v1.w);
                    kf[ct][kk] = f;
                }
            } else if (s < L) {
                const bf16* kp = &kb[((size_t)(b * T_ + s - sp) * H_ + h) * HD_];
                #pragma unroll
                for (int kk = 0; kk < 4; ++kk)
                    kf[ct][kk] = *(const bf16x8*)(kp + kk * 32 + lg * 8);
            } else {
                #pragma unroll
                for (int kk = 0; kk < 4; ++kk) {
                    bf16x8 f;
                    #pragma unroll
                    for (int j = 0; j < 8; ++j) f[j] = 0;
                    kf[ct][kk] = f;
                }
            }
        }
        COMPUTE(s0, false);
    }

    // ---- cross-wave combine ----
    if (lg == 0) {
        #pragma unroll
        for (int rt = 0; rt < 2; ++rt) {
            msh[wave][rt * 16 + li] = m_r[rt];
            lsh[wave][rt * 16 + li] = l_r[rt];
        }
    }
    __syncthreads();
    float corr2[2][4];
    #pragma unroll
    for (int rt = 0; rt < 2; ++rt)
        for (int r = 0; r < 4; ++r) {
            int row = rt * 16 + lg * 4 + r;
            float M = fmaxf(fmaxf(msh[0][row], msh[1][row]), fmaxf(msh[2][row], msh[3][row]));
            corr2[rt][r] = __expf(msh[wave][row] - M);
        }
    if (tid < 32) {
        int row = tid;
        float M = fmaxf(fmaxf(msh[0][row], msh[1][row]), fmaxf(msh[2][row], msh[3][row]));
        float lt = 0.f;
        #pragma unroll
        for (int w = 0; w < 4; ++w) lt += lsh[w][row] * __expf(msh[w][row] - M);
        ltot[row] = lt;
    }
    __syncthreads();
    for (int w = 0; w < 4; ++w) {
        if (wave == w) {
            #pragma unroll
            for (int rt = 0; rt < 2; ++rt)
                for (int ht = 0; ht < 8; ++ht)
                    for (int r = 0; r < 4; ++r) {
                        int row = rt * 16 + lg * 4 + r, col = ht * 16 + li;
                        float val = o[rt][ht][r] * corr2[rt][r];
                        if (w == 0) Osh[row][col] = val;
                        else Osh[row][col] += val;
                    }
        }
        __syncthreads();
    }
    {
        int row = tid >> 3;
        int c0 = (tid & 7) * 16;
        float inv = 1.0f / ltot[row];
        #pragma unroll
        for (int j = 0; j < 16; ++j)
            ob[(size_t)(b * T_ + row) * D_ + h * HD_ + c0 + j] = __float2bfloat16(Osh[row][c0 + j] * inv);
    }
}

extern "C" void kernel_launch(void* const* d_in, const int* in_sizes, int n_in,
                              void* d_out, int out_size, void* d_ws, size_t ws_size,
                              hipStream_t stream) {
    const float* x  = (const float*)d_in[0];
    const float* wq = (const float*)d_in[1];
    const float* wk = (const float*)d_in[2];
    const float* wv = (const float*)d_in[3];
    const float* wo = (const float*)d_in[4];
    const float* kc = (const float*)d_in[5];
    const float* vc = (const float*)d_in[6];
    const int*   sp = (const int*)d_in[7];

    char* ws = (char*)d_ws;
    const size_t MT = (size_t)M_ * D_;                 // 2M elements
    bf16* wt = (bf16*)ws;                              // 32 MiB (wo^T only)
    bf16* xb = wt + (size_t)D_ * D_;
    bf16* qb = xb + MT;
    bf16* kb = qb + MT;
    bf16* vb = kb + MT;
    bf16* ab = vb + MT;

    conv_x<<<dim3((int)(MT / 8 / 256)), 256, 0, stream>>>(x, xb);
    transpose_w<<<dim3(64, 64), 256, 0, stream>>>(wo, wt);
    gemm_qkvw<<<dim3(96, 8), 256, 0, stream>>>(xb, wq, wk, wv, qb);
    rope_inplace<<<dim3((int)(MT / 8 / 256)), 256, 0, stream>>>(qb, kb);
    attn<<<dim3(B_ * H_), 256, 0, stream>>>(qb, kb, vb, kc, vc, sp, ab);
    gemm_bf16t<64, 64><<<dim3(64, 8), 256, 0, stream>>>(ab, wt, (float*)d_out);
}

// Round 17
// 318.542 us; speedup vs baseline: 1.3317x; 1.3317x over previous
//
#include <hip/hip_runtime.h>
#include <hip/hip_bf16.h>

#define B_ 16
#define T_ 32
#define D_ 4096
#define H_ 32
#define HD_ 128
#define MAXS_ 2048
#define M_ (B_*T_)   // 512 rows

typedef __hip_bfloat16 bf16;
typedef __attribute__((ext_vector_type(8))) short bf16x8;
typedef __attribute__((ext_vector_type(4))) float f32x4;

static __device__ __forceinline__ short f2b(float f) {
    bf16 h = __float2bfloat16(f);
    return *reinterpret_cast<short*>(&h);
}
static __device__ __forceinline__ float b2f(short s) {
    bf16 h;
    *reinterpret_cast<short*>(&h) = s;
    return __bfloat162float(h);
}

// async global->LDS, 16B per lane; LDS dest is wave-uniform base + lane*16
#define GLD16(gsrc, ldst) \
    __builtin_amdgcn_global_load_lds((const __attribute__((address_space(1))) void*)(gsrc), \
        (__attribute__((address_space(3))) void*)(ldst), 16, 0, 0)

// ---------------- x f32 -> bf16 ----------------
__global__ __launch_bounds__(256) void conv_x(const float* __restrict__ x, bf16* __restrict__ xb) {
    int idx = blockIdx.x * 256 + threadIdx.x;   // 8-element unit
    const float4* xf = (const float4*)x;
    float4 a = xf[idx * 2], b = xf[idx * 2 + 1];
    bf16x8 o;
    o[0] = f2b(a.x); o[1] = f2b(a.y); o[2] = f2b(a.z); o[3] = f2b(a.w);
    o[4] = f2b(b.x); o[5] = f2b(b.y); o[6] = f2b(b.z); o[7] = f2b(b.w);
    *(bf16x8*)&xb[(size_t)idx * 8] = o;
}

// ---------------- single W [k][n] f32 -> Wt [n][k] bf16 (wo only) ----------------
__global__ __launch_bounds__(256) void transpose_w(const float* __restrict__ W, bf16* __restrict__ wt) {
    __shared__ float Ts[64][65];
    const int n0 = blockIdx.x * 64, k0 = blockIdx.y * 64;
    const int t = threadIdx.x;
    {
        int kk = t >> 4, nn = (t & 15) * 4;
        #pragma unroll
        for (int r = 0; r < 4; ++r) {
            float4 v = *(const float4*)&W[(size_t)(k0 + kk + 16 * r) * D_ + n0 + nn];
            Ts[kk + 16 * r][nn + 0] = v.x;
            Ts[kk + 16 * r][nn + 1] = v.y;
            Ts[kk + 16 * r][nn + 2] = v.z;
            Ts[kk + 16 * r][nn + 3] = v.w;
        }
    }
    __syncthreads();
    const int kg = t & 7, nr = t >> 3;
    #pragma unroll
    for (int r = 0; r < 2; ++r) {
        int n = nr + 32 * r;
        bf16x8 o;
        #pragma unroll
        for (int j = 0; j < 8; ++j) o[j] = f2b(Ts[kg * 8 + j][n]);
        *(bf16x8*)&wt[(size_t)(n0 + n) * D_ + k0 + kg * 8] = o;
    }
}

// ---------------- QKV GEMM, fused weight transpose+convert, BK=64 (2x 32-k halves) ----------------
__global__ __launch_bounds__(256) void gemm_qkvw(const bf16* __restrict__ A,
        const float* __restrict__ wq, const float* __restrict__ wk,
        const float* __restrict__ wv, bf16* __restrict__ out) {
    const int K = D_;
    const int wsel = blockIdx.x >> 5;
    const float* W = (wsel == 0) ? wq : (wsel == 1) ? wk : wv;
    const int lcol0 = (blockIdx.x & 31) * 128;
    bf16* Ob = out + (size_t)wsel * M_ * D_;
    __shared__ bf16 As[2][64 * 32];
    __shared__ short Bs[2][128][40];
    const int tid = threadIdx.x, lane = tid & 63, wave = tid >> 6;
    const int wr = wave >> 1, wc = wave & 1;
    const int lg = lane >> 4, li = lane & 15;
    const int row0 = blockIdx.y * 64;
    const int bq = tid & 31, kq = tid >> 5;
    f32x4 acc[2][4];
    #pragma unroll
    for (int i = 0; i < 2; ++i)
        #pragma unroll
        for (int j = 0; j < 4; ++j)
            #pragma unroll
            for (int r = 0; r < 4; ++r) acc[i][j][r] = 0.f;

    const int sw = (li & 3) << 4;
    for (int k0 = 0; k0 < K; k0 += 64) {
        float4 wv4[2][4];
        #pragma unroll
        for (int h = 0; h < 2; ++h)
            #pragma unroll
            for (int i = 0; i < 4; ++i)
                wv4[h][i] = *(const float4*)&W[(size_t)(k0 + 32 * h + kq * 4 + i) * D_ + lcol0 + bq * 4];
        {
            int X = tid * 16;
            int row = X >> 6;
            int kb = (X & 63) ^ ((row & 3) << 4);
            GLD16(A + (size_t)(row0 + row) * K + k0 + (kb >> 1),      (char*)As[0] + wave * 1024);
            GLD16(A + (size_t)(row0 + row) * K + k0 + 32 + (kb >> 1), (char*)As[1] + wave * 1024);
        }
        #pragma unroll
        for (int h = 0; h < 2; ++h)
            #pragma unroll
            for (int j = 0; j < 4; ++j) {
                int n = bq * 4 + j;
                short4 col;
                col.x = f2b(((const float*)&wv4[h][0])[j]);
                col.y = f2b(((const float*)&wv4[h][1])[j]);
                col.z = f2b(((const float*)&wv4[h][2])[j]);
                col.w = f2b(((const float*)&wv4[h][3])[j]);
                *(short4*)((char*)&Bs[h][n][0] + ((kq * 8) ^ (((n >> 4) & 3) << 4))) = col;
            }
        __syncthreads();
        bf16x8 af[2][2], bfr[2][4];
        #pragma unroll
        for (int h = 0; h < 2; ++h) {
            #pragma unroll
            for (int i = 0; i < 2; ++i) {
                int row = wr * 32 + i * 16 + li;
                af[h][i] = *(const bf16x8*)((const char*)As[h] + row * 64 + ((lg * 16) ^ sw));
            }
            #pragma unroll
            for (int j = 0; j < 4; ++j) {
                int row = wc * 64 + j * 16 + li;
                bfr[h][j] = *(const bf16x8*)((const char*)&Bs[h][row][0] + ((lg * 16) ^ (((row >> 4) & 3) << 4)));
            }
        }
        #pragma unroll
        for (int h = 0; h < 2; ++h)
            #pragma unroll
            for (int i = 0; i < 2; ++i)
                #pragma unroll
                for (int j = 0; j < 4; ++j)
                    acc[i][j] = __builtin_amdgcn_mfma_f32_16x16x32_bf16(af[h][i], bfr[h][j], acc[i][j], 0, 0, 0);
        __syncthreads();
    }
    #pragma unroll
    for (int i = 0; i < 2; ++i)
        for (int j = 0; j < 4; ++j)
            for (int r = 0; r < 4; ++r) {
                int row = row0 + wr * 32 + i * 16 + lg * 4 + r;
                int col = lcol0 + wc * 64 + j * 16 + li;
                Ob[(size_t)row * D_ + col] = __float2bfloat16(acc[i][j][r]);
            }
}

// ---------------- bf16 GEMM (pre-transposed Bt), BK=64 via 2x 32-k halves — used for wo ----------------
template<int BM, int BN>
__global__ __launch_bounds__(256) void gemm_bf16t(const bf16* __restrict__ A,
        const bf16* __restrict__ Bt, float* __restrict__ O) {
    constexpr int IM = BM / 32;
    constexpr int JN = BN / 32;
    constexpr int nA = (BM * 64) / 4096;
    constexpr int nB = (BN * 64) / 4096;
    const int K = D_;
    __shared__ bf16 As[2][BM * 32];
    __shared__ bf16 Bs[2][BN * 32];
    const int tid = threadIdx.x, lane = tid & 63, wave = tid >> 6;
    const int wr = wave >> 1, wc = wave & 1;
    const int lg = lane >> 4, li = lane & 15;
    const int row0 = blockIdx.y * BM, col0 = blockIdx.x * BN;
    f32x4 acc[IM][JN];
    #pragma unroll
    for (int i = 0; i < IM; ++i)
        #pragma unroll
        for (int j = 0; j < JN; ++j)
            #pragma unroll
            for (int r = 0; r < 4; ++r) acc[i][j][r] = 0.f;

    const int sw = (li & 3) << 4;
    for (int k0 = 0; k0 < K; k0 += 64) {
        #pragma unroll
        for (int h = 0; h < 2; ++h) {
            #pragma unroll
            for (int i = 0; i < nA; ++i) {
                int X = (i * 256 + tid) * 16;
                int row = X >> 6;
                int kb = (X & 63) ^ ((row & 3) << 4);
                GLD16(A + (size_t)(row0 + row) * K + k0 + 32 * h + (kb >> 1),
                      (char*)As[h] + (i * 256 + wave * 64) * 16);
            }
            #pragma unroll
            for (int i = 0; i < nB; ++i) {
                int X = (i * 256 + tid) * 16;
                int row = X >> 6;
                int kb = (X & 63) ^ ((row & 3) << 4);
                GLD16(Bt + (size_t)(col0 + row) * K + k0 + 32 * h + (kb >> 1),
                      (char*)Bs[h] + (i * 256 + wave * 64) * 16);
            }
        }
        __syncthreads();
        bf16x8 af[2][IM], bfr[2][JN];
        #pragma unroll
        for (int h = 0; h < 2; ++h) {
            #pragma unroll
            for (int i = 0; i < IM; ++i) {
                int row = wr * (BM / 2) + i * 16 + li;
                af[h][i] = *(const bf16x8*)((const char*)As[h] + row * 64 + ((lg * 16) ^ sw));
            }
            #pragma unroll
            for (int j = 0; j < JN; ++j) {
                int row = wc * (BN / 2) + j * 16 + li;
                bfr[h][j] = *(const bf16x8*)((const char*)Bs[h] + row * 64 + ((lg * 16) ^ sw));
            }
        }
        #pragma unroll
        for (int h = 0; h < 2; ++h)
            #pragma unroll
            for (int i = 0; i < IM; ++i)
                #pragma unroll
                for (int j = 0; j < JN; ++j)
                    acc[i][j] = __builtin_amdgcn_mfma_f32_16x16x32_bf16(af[h][i], bfr[h][j], acc[i][j], 0, 0, 0);
        __syncthreads();
    }
    #pragma unroll
    for (int i = 0; i < IM; ++i)
        for (int j = 0; j < JN; ++j)
            for (int r = 0; r < 4; ++r) {
                int row = row0 + wr * (BM / 2) + i * 16 + lg * 4 + r;
                int col = col0 + wc * (BN / 2) + j * 16 + li;
                O[(size_t)row * D_ + col] = acc[i][j][r];
            }
}

// ---------------- RoPE in-place on bf16 q,k ----------------
__global__ __launch_bounds__(256) void rope_inplace(bf16* __restrict__ qb, bf16* __restrict__ kb) {
    int idx = blockIdx.x * 256 + threadIdx.x;
    size_t e0 = (size_t)idx * 8;
    int hd0 = (int)(e0 & 127);
    int t = (int)((e0 >> 12) & 31);
    bf16x8 q = *(bf16x8*)&qb[e0];
    bf16x8 k = *(bf16x8*)&kb[e0];
    bf16x8 qo, ko;
    #pragma unroll
    for (int p = 0; p < 4; ++p) {
        int i = (hd0 >> 1) + p;
        float theta = exp2f(-(float)i * 0.41524101186092787f);  // log2(10000)/32
        float s, c;
        sincosf((float)t * theta, &s, &c);
        float q0 = b2f(q[2 * p]), q1 = b2f(q[2 * p + 1]);
        qo[2 * p]     = f2b(q0 * c - q1 * s);
        qo[2 * p + 1] = f2b(q1 * c + q0 * s);
        float k0 = b2f(k[2 * p]), k1 = b2f(k[2 * p + 1]);
        ko[2 * p]     = f2b(k0 * c - k1 * s);
        ko[2 * p + 1] = f2b(k1 * c + k0 * s);
    }
    *(bf16x8*)&qb[e0] = qo;
    *(bf16x8*)&kb[e0] = ko;
}

// ---------------- Fused flash attention: deep async staging (gload_lds V + reg-prefetch K) ----------------
__global__ __launch_bounds__(256, 2) void attn(const bf16* __restrict__ qb,
        const bf16* __restrict__ kb, const bf16* __restrict__ vb,
        const float* __restrict__ kc, const float* __restrict__ vc,
        const int* __restrict__ spp, bf16* __restrict__ ob) {
    const int bh = blockIdx.x;
    const int b = bh >> 5, h = bh & 31;
    const int sp = *spp;
    const int L = sp + T_;
    const int tid = threadIdx.x, lane = tid & 63, wave = tid >> 6;
    const int lg = lane >> 4, li = lane & 15;

    __shared__ __align__(16) char smem[76928];
    char* VLDSw = smem + wave * 16384;
    float(*Vf)[128] = (float(*)[128])VLDSw;
    auto Plds = (bf16(*)[32][40])(smem + 65536);
    auto msh  = (float(*)[32])(smem + 75776);
    auto lsh  = (float(*)[32])(smem + 76288);
    float* ltot = (float*)(smem + 76800);
    float(*Osh)[128] = (float(*)[128])smem;            // post-loop overlay

    bf16x8 qf[2][4];
    #pragma unroll
    for (int rt = 0; rt < 2; ++rt)
        #pragma unroll
        for (int kk = 0; kk < 4; ++kk)
            qf[rt][kk] = *(const bf16x8*)(&qb[((size_t)(b * T_ + rt * 16 + li) * H_ + h) * HD_ + kk * 32 + lg * 8]);

    f32x4 o[2][8];
    float m_r[2], l_r[2];
    m_r[0] = m_r[1] = -1e30f;
    l_r[0] = l_r[1] = 0.f;
    #pragma unroll
    for (int rt = 0; rt < 2; ++rt) for (int ht = 0; ht < 8; ++ht) for (int r = 0; r < 4; ++r) o[rt][ht][r] = 0.f;

    const float scale = 0.08838834764831845f;  // 1/sqrt(128)
    const int nch = (L + 31) >> 5;
    const int ccache = sp >> 5;

    bf16x8 kf[2][4];
    float4 kr[16];

    auto KISSUE = [&](int cc) {
        #pragma unroll
        for (int ct = 0; ct < 2; ++ct) {
            const float* kp = &kc[(((size_t)b * MAXS_ + cc * 32 + ct * 16 + li) * H_ + h) * HD_ + lg * 8];
            #pragma unroll
            for (int kk = 0; kk < 4; ++kk) {
                kr[ct * 8 + 2 * kk]     = *(const float4*)(kp + kk * 32);
                kr[ct * 8 + 2 * kk + 1] = *(const float4*)(kp + kk * 32 + 4);
            }
        }
    };
    auto VSTAGE = [&](int cc) {
        const float* src = vc + (((size_t)b * MAXS_ + cc * 32) * H_ + h) * HD_;
        #pragma unroll
        for (int i = 0; i < 16; ++i) {
            GLD16(src + (size_t)(2 * i + (lane >> 5)) * (H_ * HD_) + (lane & 31) * 4,
                  VLDSw + i * 1024);
        }
    };
    auto KBUILD = [&]() {
        #pragma unroll
        for (int ct = 0; ct < 2; ++ct)
            #pragma unroll
            for (int kk = 0; kk < 4; ++kk) {
                bf16x8 f;
                f[0] = f2b(kr[ct * 8 + 2 * kk].x); f[1] = f2b(kr[ct * 8 + 2 * kk].y);
                f[2] = f2b(kr[ct * 8 + 2 * kk].z); f[3] = f2b(kr[ct * 8 + 2 * kk].w);
                f[4] = f2b(kr[ct * 8 + 2 * kk + 1].x); f[5] = f2b(kr[ct * 8 + 2 * kk + 1].y);
                f[6] = f2b(kr[ct * 8 + 2 * kk + 1].z); f[7] = f2b(kr[ct * 8 + 2 * kk + 1].w);
                kf[ct][kk] = f;
            }
    };

    auto COMPUTE = [&](int s0, bool deep) {
        f32x4 sc[2][2];
        #pragma unroll
        for (int ct = 0; ct < 2; ++ct)
            #pragma unroll
            for (int rt = 0; rt < 2; ++rt) {
                f32x4 acc;
                for (int r = 0; r < 4; ++r) acc[r] = 0.f;
                #pragma unroll
                for (int kk = 0; kk < 4; ++kk)
                    acc = __builtin_amdgcn_mfma_f32_16x16x32_bf16(kf[ct][kk], qf[rt][kk], acc, 0, 0, 0);
                sc[ct][rt] = acc;
            }
        float corr[2];
        #pragma unroll
        for (int rt = 0; rt < 2; ++rt) {
            float xv[8];
            #pragma unroll
            for (int ct = 0; ct < 2; ++ct)
                #pragma unroll
                for (int r = 0; r < 4; ++r) {
                    float xx = sc[ct][rt][r] * scale;
                    if (s0 + ct * 16 + 4 * lg + r >= L) xx = -1e30f;
                    xv[ct * 4 + r] = xx;
                }
            float mx = fmaxf(fmaxf(fmaxf(xv[0], xv[1]), fmaxf(xv[2], xv[3])),
                             fmaxf(fmaxf(xv[4], xv[5]), fmaxf(xv[6], xv[7])));
            mx = fmaxf(mx, __shfl_xor(mx, 16, 64));
            mx = fmaxf(mx, __shfl_xor(mx, 32, 64));
            float mnew = fmaxf(m_r[rt], mx);
            corr[rt] = __expf(m_r[rt] - mnew);
            float p[8], ssum = 0.f;
            #pragma unroll
            for (int j = 0; j < 8; ++j) { p[j] = __expf(xv[j] - mnew); ssum += p[j]; }
            ssum += __shfl_xor(ssum, 16, 64);
            ssum += __shfl_xor(ssum, 32, 64);
            l_r[rt] = l_r[rt] * corr[rt] + ssum;
            m_r[rt] = mnew;
            #pragma unroll
            for (int ct = 0; ct < 2; ++ct)
                #pragma unroll
                for (int r = 0; r < 4; ++r)
                    Plds[wave][rt * 16 + li][ct * 16 + 4 * lg + r] = __float2bfloat16(p[ct * 4 + r]);
        }
        #pragma unroll
        for (int rt = 0; rt < 2; ++rt) {
            float cq[4];
            #pragma unroll
            for (int r = 0; r < 4; ++r) cq[r] = __shfl(corr[rt], 20 * lg + r, 64);
            #pragma unroll
            for (int ht = 0; ht < 8; ++ht)
                #pragma unroll
                for (int r = 0; r < 4; ++r) o[rt][ht][r] *= cq[r];
        }
        if (deep) asm volatile("s_waitcnt vmcnt(16) lgkmcnt(0)" ::: "memory");
        else      asm volatile("s_waitcnt vmcnt(0) lgkmcnt(0)" ::: "memory");
        __builtin_amdgcn_sched_barrier(0);
        bf16x8 pf[2];
        pf[0] = *(const bf16x8*)(&Plds[wave][li][lg * 8]);
        pf[1] = *(const bf16x8*)(&Plds[wave][16 + li][lg * 8]);
        #pragma unroll
        for (int ht = 0; ht < 8; ++ht) {
            bf16x8 vf;
            #pragma unroll
            for (int j = 0; j < 8; ++j)
                vf[j] = f2b(Vf[lg * 8 + j][ht * 16 + li]);
            #pragma unroll
            for (int rt = 0; rt < 2; ++rt)
                o[rt][ht] = __builtin_amdgcn_mfma_f32_16x16x32_bf16(pf[rt], vf, o[rt][ht], 0, 0, 0);
        }
    };

    int c = wave;
    if (c < ccache) {
        KISSUE(c);
        VSTAGE(c);
        for (;;) {
            const int s0 = c * 32;
            const int nc = c + 4;
            const bool more = nc < ccache;
            KBUILD();
            if (more) KISSUE(nc);
            COMPUTE(s0, more);
            asm volatile("s_waitcnt lgkmcnt(0)" ::: "memory");
            if (more) VSTAGE(nc);
            c = nc;
            if (!more) break;
        }
    }
    for (; c < nch; c += 4) {
        const int s0 = c * 32;
        #pragma unroll
        for (int u = 0; u < 16; ++u) {
            int F = lane + 64 * u;
            int s = F >> 5, q = F & 31;
            int ss = s0 + s;
            float4 v;
            if (ss < sp) {
                v = *(const float4*)&vc[(((size_t)b * MAXS_ + ss) * H_ + h) * HD_ + q * 4];
            } else if (ss < L) {
                ushort4 uu = *(const ushort4*)&vb[(((size_t)b * T_ + (ss - sp)) * H_ + h) * HD_ + q * 4];
                v = make_float4(b2f((short)uu.x), b2f((short)uu.y), b2f((short)uu.z), b2f((short)uu.w));
            } else {
                v = make_float4(0.f, 0.f, 0.f, 0.f);
            }
            *(float4*)&Vf[s][q * 4] = v;
        }
        #pragma unroll
        for (int ct = 0; ct < 2; ++ct) {
            int s = s0 + ct * 16 + li;
            if (s < sp) {
                const float* kp = &kc[(((size_t)b * MAXS_ + s) * H_ + h) * HD_];
                #pragma unroll
                for (int kk = 0; kk < 4; ++kk) {
                    float4 v0 = *(const float4*)(&kp[kk * 32 + lg * 8]);
                    float4 v1 = *(const float4*)(&kp[kk * 32 + lg * 8 + 4]);
                    bf16x8 f;
                    f[0] = f2b(v0.x); f[1] = f2b(v0.y); f[2] = f2b(v0.z); f[3] = f2b(v0.w);
                    f[4] = f2b(v1.x); f[5] = f2b(v1.y); f[6] = f2b(v1.z); f[7] = f2b(v1.w);
                    kf[ct][kk] = f;
                }
            } else if (s < L) {
                const bf16* kp = &kb[((size_t)(b * T_ + s - sp) * H_ + h) * HD_];
                #pragma unroll
                for (int kk = 0; kk < 4; ++kk)
                    kf[ct][kk] = *(const bf16x8*)(kp + kk * 32 + lg * 8);
            } else {
                #pragma unroll
                for (int kk = 0; kk < 4; ++kk) {
                    bf16x8 f;
                    #pragma unroll
                    for (int j = 0; j < 8; ++j) f[j] = 0;
                    kf[ct][kk] = f;
                }
            }
        }
        COMPUTE(s0, false);
    }

    // ---- cross-wave combine ----
    if (lg == 0) {
        #pragma unroll
        for (int rt = 0; rt < 2; ++rt) {
            msh[wave][rt * 16 + li] = m_r[rt];
            lsh[wave][rt * 16 + li] = l_r[rt];
        }
    }
    __syncthreads();
    float corr2[2][4];
    #pragma unroll
    for (int rt = 0; rt < 2; ++rt)
        for (int r = 0; r < 4; ++r) {
            int row = rt * 16 + lg * 4 + r;
            float M = fmaxf(fmaxf(msh[0][row], msh[1][row]), fmaxf(msh[2][row], msh[3][row]));
            corr2[rt][r] = __expf(msh[wave][row] - M);
        }
    if (tid < 32) {
        int row = tid;
        float M = fmaxf(fmaxf(msh[0][row], msh[1][row]), fmaxf(msh[2][row], msh[3][row]));
        float lt = 0.f;
        #pragma unroll
        for (int w = 0; w < 4; ++w) lt += lsh[w][row] * __expf(msh[w][row] - M);
        ltot[row] = lt;
    }
    __syncthreads();
    for (int w = 0; w < 4; ++w) {
        if (wave == w) {
            #pragma unroll
            for (int rt = 0; rt < 2; ++rt)
                for (int ht = 0; ht < 8; ++ht)
                    for (int r = 0; r < 4; ++r) {
                        int row = rt * 16 + lg * 4 + r, col = ht * 16 + li;
                        float val = o[rt][ht][r] * corr2[rt][r];
                        if (w == 0) Osh[row][col] = val;
                        else Osh[row][col] += val;
                    }
        }
        __syncthreads();
    }
    {
        int row = tid >> 3;
        int c0 = (tid & 7) * 16;
        float inv = 1.0f / ltot[row];
        #pragma unroll
        for (int j = 0; j < 16; ++j)
            ob[(size_t)(b * T_ + row) * D_ + h * HD_ + c0 + j] = __float2bfloat16(Osh[row][c0 + j] * inv);
    }
}

extern "C" void kernel_launch(void* const* d_in, const int* in_sizes, int n_in,
                              void* d_out, int out_size, void* d_ws, size_t ws_size,
                              hipStream_t stream) {
    const float* x  = (const float*)d_in[0];
    const float* wq = (const float*)d_in[1];
    const float* wk = (const float*)d_in[2];
    const float* wv = (const float*)d_in[3];
    const float* wo = (const float*)d_in[4];
    const float* kc = (const float*)d_in[5];
    const float* vc = (const float*)d_in[6];
    const int*   sp = (const int*)d_in[7];

    char* ws = (char*)d_ws;
    const size_t MT = (size_t)M_ * D_;                 // 2M elements
    bf16* wt = (bf16*)ws;                              // 32 MiB (wo^T only)
    bf16* xb = wt + (size_t)D_ * D_;
    bf16* qb = xb + MT;
    bf16* kb = qb + MT;
    bf16* vb = kb + MT;
    bf16* ab = vb + MT;

    conv_x<<<dim3((int)(MT / 8 / 256)), 256, 0, stream>>>(x, xb);
    transpose_w<<<dim3(64, 64), 256, 0, stream>>>(wo, wt);
    gemm_qkvw<<<dim3(96, 8), 256, 0, stream>>>(xb, wq, wk, wv, qb);
    rope_inplace<<<dim3((int)(MT / 8 / 256)), 256, 0, stream>>>(qb, kb);
    attn<<<dim3(B_ * H_), 256, 0, stream>>>(qb, kb, vb, kc, vc, sp, ab);
    gemm_bf16t<64, 64><<<dim3(64, 8), 256, 0, stream>>>(ab, wt, (float*)d_out);
}

// Round 18
// 304.261 us; speedup vs baseline: 1.3942x; 1.0469x over previous
//
#include <hip/hip_runtime.h>
#include <hip/hip_bf16.h>

#define B_ 16
#define T_ 32
#define D_ 4096
#define H_ 32
#define HD_ 128
#define MAXS_ 2048
#define M_ (B_*T_)   // 512 rows

typedef __hip_bfloat16 bf16;
typedef __attribute__((ext_vector_type(8))) short bf16x8;
typedef __attribute__((ext_vector_type(4))) float f32x4;

static __device__ __forceinline__ short f2b(float f) {
    bf16 h = __float2bfloat16(f);
    return *reinterpret_cast<short*>(&h);
}
static __device__ __forceinline__ float b2f(short s) {
    bf16 h;
    *reinterpret_cast<short*>(&h) = s;
    return __bfloat162float(h);
}

// async global->LDS, 16B per lane; LDS dest is wave-uniform base + lane*16
#define GLD16(gsrc, ldst) \
    __builtin_amdgcn_global_load_lds((const __attribute__((address_space(1))) void*)(gsrc), \
        (__attribute__((address_space(3))) void*)(ldst), 16, 0, 0)

// ---------------- x f32 -> bf16 ----------------
__global__ __launch_bounds__(256) void conv_x(const float* __restrict__ x, bf16* __restrict__ xb) {
    int idx = blockIdx.x * 256 + threadIdx.x;   // 8-element unit
    const float4* xf = (const float4*)x;
    float4 a = xf[idx * 2], b = xf[idx * 2 + 1];
    bf16x8 o;
    o[0] = f2b(a.x); o[1] = f2b(a.y); o[2] = f2b(a.z); o[3] = f2b(a.w);
    o[4] = f2b(b.x); o[5] = f2b(b.y); o[6] = f2b(b.z); o[7] = f2b(b.w);
    *(bf16x8*)&xb[(size_t)idx * 8] = o;
}

// ---------------- QKV GEMM, fused weight transpose+convert, BK=64 (2x 32-k halves) ----------------
__global__ __launch_bounds__(256) void gemm_qkvw(const bf16* __restrict__ A,
        const float* __restrict__ wq, const float* __restrict__ wk,
        const float* __restrict__ wv, bf16* __restrict__ out) {
    const int K = D_;
    const int wsel = blockIdx.x >> 5;
    const float* W = (wsel == 0) ? wq : (wsel == 1) ? wk : wv;
    const int lcol0 = (blockIdx.x & 31) * 128;
    bf16* Ob = out + (size_t)wsel * M_ * D_;
    __shared__ bf16 As[2][64 * 32];
    __shared__ short Bs[2][128][40];
    const int tid = threadIdx.x, lane = tid & 63, wave = tid >> 6;
    const int wr = wave >> 1, wc = wave & 1;
    const int lg = lane >> 4, li = lane & 15;
    const int row0 = blockIdx.y * 64;
    const int bq = tid & 31, kq = tid >> 5;
    f32x4 acc[2][4];
    #pragma unroll
    for (int i = 0; i < 2; ++i)
        #pragma unroll
        for (int j = 0; j < 4; ++j)
            #pragma unroll
            for (int r = 0; r < 4; ++r) acc[i][j][r] = 0.f;

    const int sw = (li & 3) << 4;
    for (int k0 = 0; k0 < K; k0 += 64) {
        float4 wv4[2][4];
        #pragma unroll
        for (int h = 0; h < 2; ++h)
            #pragma unroll
            for (int i = 0; i < 4; ++i)
                wv4[h][i] = *(const float4*)&W[(size_t)(k0 + 32 * h + kq * 4 + i) * D_ + lcol0 + bq * 4];
        {
            int X = tid * 16;
            int row = X >> 6;
            int kb = (X & 63) ^ ((row & 3) << 4);
            GLD16(A + (size_t)(row0 + row) * K + k0 + (kb >> 1),      (char*)As[0] + wave * 1024);
            GLD16(A + (size_t)(row0 + row) * K + k0 + 32 + (kb >> 1), (char*)As[1] + wave * 1024);
        }
        #pragma unroll
        for (int h = 0; h < 2; ++h)
            #pragma unroll
            for (int j = 0; j < 4; ++j) {
                int n = bq * 4 + j;
                short4 col;
                col.x = f2b(((const float*)&wv4[h][0])[j]);
                col.y = f2b(((const float*)&wv4[h][1])[j]);
                col.z = f2b(((const float*)&wv4[h][2])[j]);
                col.w = f2b(((const float*)&wv4[h][3])[j]);
                *(short4*)((char*)&Bs[h][n][0] + ((kq * 8) ^ (((n >> 4) & 3) << 4))) = col;
            }
        __syncthreads();
        bf16x8 af[2][2], bfr[2][4];
        #pragma unroll
        for (int h = 0; h < 2; ++h) {
            #pragma unroll
            for (int i = 0; i < 2; ++i) {
                int row = wr * 32 + i * 16 + li;
                af[h][i] = *(const bf16x8*)((const char*)As[h] + row * 64 + ((lg * 16) ^ sw));
            }
            #pragma unroll
            for (int j = 0; j < 4; ++j) {
                int row = wc * 64 + j * 16 + li;
                bfr[h][j] = *(const bf16x8*)((const char*)&Bs[h][row][0] + ((lg * 16) ^ (((row >> 4) & 3) << 4)));
            }
        }
        #pragma unroll
        for (int h = 0; h < 2; ++h)
            #pragma unroll
            for (int i = 0; i < 2; ++i)
                #pragma unroll
                for (int j = 0; j < 4; ++j)
                    acc[i][j] = __builtin_amdgcn_mfma_f32_16x16x32_bf16(af[h][i], bfr[h][j], acc[i][j], 0, 0, 0);
        __syncthreads();
    }
    #pragma unroll
    for (int i = 0; i < 2; ++i)
        for (int j = 0; j < 4; ++j)
            for (int r = 0; r < 4; ++r) {
                int row = row0 + wr * 32 + i * 16 + lg * 4 + r;
                int col = lcol0 + wc * 64 + j * 16 + li;
                Ob[(size_t)row * D_ + col] = __float2bfloat16(acc[i][j][r]);
            }
}

// ---------------- wo GEMM, fused weight transpose+convert, BK=64, BN=64, f32 out ----------------
// A: ab bf16 [512][4096] via gload_lds. W: raw f32 wo [k][n], reg-transposed to Bs.
// 256 threads stage the full 64k x 64n f32 tile per step (thread = 4k x 4n unit).
__global__ __launch_bounds__(256) void gemm_wof(const bf16* __restrict__ A,
        const float* __restrict__ W, float* __restrict__ O) {
    const int K = D_;
    const int lcol0 = blockIdx.x * 64;
    __shared__ bf16 As[2][64 * 32];
    __shared__ short Bs[2][64][40];
    const int tid = threadIdx.x, lane = tid & 63, wave = tid >> 6;
    const int wr = wave >> 1, wc = wave & 1;
    const int lg = lane >> 4, li = lane & 15;
    const int row0 = blockIdx.y * 64;
    const int bq = tid & 15, kq = tid >> 4;   // staging unit: 4k x 4n, kq 0..15 covers 64k
    f32x4 acc[2][2];
    #pragma unroll
    for (int i = 0; i < 2; ++i)
        #pragma unroll
        for (int j = 0; j < 2; ++j)
            #pragma unroll
            for (int r = 0; r < 4; ++r) acc[i][j][r] = 0.f;

    const int sw = (li & 3) << 4;
    for (int k0 = 0; k0 < K; k0 += 64) {
        float4 wv4[4];
        #pragma unroll
        for (int i = 0; i < 4; ++i)
            wv4[i] = *(const float4*)&W[(size_t)(k0 + kq * 4 + i) * D_ + lcol0 + bq * 4];
        {
            int X = tid * 16;
            int row = X >> 6;
            int kb = (X & 63) ^ ((row & 3) << 4);
            GLD16(A + (size_t)(row0 + row) * K + k0 + (kb >> 1),      (char*)As[0] + wave * 1024);
            GLD16(A + (size_t)(row0 + row) * K + k0 + 32 + (kb >> 1), (char*)As[1] + wave * 1024);
        }
        const int h = kq >> 3, kl = kq & 7;
        #pragma unroll
        for (int j = 0; j < 4; ++j) {
            int n = bq * 4 + j;
            short4 col;
            col.x = f2b(((const float*)&wv4[0])[j]);
            col.y = f2b(((const float*)&wv4[1])[j]);
            col.z = f2b(((const float*)&wv4[2])[j]);
            col.w = f2b(((const float*)&wv4[3])[j]);
            *(short4*)((char*)&Bs[h][n][0] + ((kl * 8) ^ (((n >> 4) & 3) << 4))) = col;
        }
        __syncthreads();
        bf16x8 af[2][2], bfr[2][2];
        #pragma unroll
        for (int h2 = 0; h2 < 2; ++h2) {
            #pragma unroll
            for (int i = 0; i < 2; ++i) {
                int row = wr * 32 + i * 16 + li;
                af[h2][i] = *(const bf16x8*)((const char*)As[h2] + row * 64 + ((lg * 16) ^ sw));
            }
            #pragma unroll
            for (int j = 0; j < 2; ++j) {
                int row = wc * 32 + j * 16 + li;
                bfr[h2][j] = *(const bf16x8*)((const char*)&Bs[h2][row][0] + ((lg * 16) ^ (((row >> 4) & 3) << 4)));
            }
        }
        #pragma unroll
        for (int h2 = 0; h2 < 2; ++h2)
            #pragma unroll
            for (int i = 0; i < 2; ++i)
                #pragma unroll
                for (int j = 0; j < 2; ++j)
                    acc[i][j] = __builtin_amdgcn_mfma_f32_16x16x32_bf16(af[h2][i], bfr[h2][j], acc[i][j], 0, 0, 0);
        __syncthreads();
    }
    #pragma unroll
    for (int i = 0; i < 2; ++i)
        for (int j = 0; j < 2; ++j)
            for (int r = 0; r < 4; ++r) {
                int row = row0 + wr * 32 + i * 16 + lg * 4 + r;
                int col = lcol0 + wc * 32 + j * 16 + li;
                O[(size_t)row * D_ + col] = acc[i][j][r];
            }
}

// ---------------- RoPE in-place on bf16 q,k ----------------
__global__ __launch_bounds__(256) void rope_inplace(bf16* __restrict__ qb, bf16* __restrict__ kb) {
    int idx = blockIdx.x * 256 + threadIdx.x;
    size_t e0 = (size_t)idx * 8;
    int hd0 = (int)(e0 & 127);
    int t = (int)((e0 >> 12) & 31);
    bf16x8 q = *(bf16x8*)&qb[e0];
    bf16x8 k = *(bf16x8*)&kb[e0];
    bf16x8 qo, ko;
    #pragma unroll
    for (int p = 0; p < 4; ++p) {
        int i = (hd0 >> 1) + p;
        float theta = exp2f(-(float)i * 0.41524101186092787f);  // log2(10000)/32
        float s, c;
        sincosf((float)t * theta, &s, &c);
        float q0 = b2f(q[2 * p]), q1 = b2f(q[2 * p + 1]);
        qo[2 * p]     = f2b(q0 * c - q1 * s);
        qo[2 * p + 1] = f2b(q1 * c + q0 * s);
        float k0 = b2f(k[2 * p]), k1 = b2f(k[2 * p + 1]);
        ko[2 * p]     = f2b(k0 * c - k1 * s);
        ko[2 * p + 1] = f2b(k1 * c + k0 * s);
    }
    *(bf16x8*)&qb[e0] = qo;
    *(bf16x8*)&kb[e0] = ko;
}

// ---------------- Fused flash attention: deep async staging (gload_lds V + reg-prefetch K) ----------------
__global__ __launch_bounds__(256, 2) void attn(const bf16* __restrict__ qb,
        const bf16* __restrict__ kb, const bf16* __restrict__ vb,
        const float* __restrict__ kc, const float* __restrict__ vc,
        const int* __restrict__ spp, bf16* __restrict__ ob) {
    const int bh = blockIdx.x;
    const int b = bh >> 5, h = bh & 31;
    const int sp = *spp;
    const int L = sp + T_;
    const int tid = threadIdx.x, lane = tid & 63, wave = tid >> 6;
    const int lg = lane >> 4, li = lane & 15;

    __shared__ __align__(16) char smem[76928];
    char* VLDSw = smem + wave * 16384;
    float(*Vf)[128] = (float(*)[128])VLDSw;
    auto Plds = (bf16(*)[32][40])(smem + 65536);
    auto msh  = (float(*)[32])(smem + 75776);
    auto lsh  = (float(*)[32])(smem + 76288);
    float* ltot = (float*)(smem + 76800);
    float(*Osh)[128] = (float(*)[128])smem;            // post-loop overlay

    bf16x8 qf[2][4];
    #pragma unroll
    for (int rt = 0; rt < 2; ++rt)
        #pragma unroll
        for (int kk = 0; kk < 4; ++kk)
            qf[rt][kk] = *(const bf16x8*)(&qb[((size_t)(b * T_ + rt * 16 + li) * H_ + h) * HD_ + kk * 32 + lg * 8]);

    f32x4 o[2][8];
    float m_r[2], l_r[2];
    m_r[0] = m_r[1] = -1e30f;
    l_r[0] = l_r[1] = 0.f;
    #pragma unroll
    for (int rt = 0; rt < 2; ++rt) for (int ht = 0; ht < 8; ++ht) for (int r = 0; r < 4; ++r) o[rt][ht][r] = 0.f;

    const float scale = 0.08838834764831845f;  // 1/sqrt(128)
    const int nch = (L + 31) >> 5;
    const int ccache = sp >> 5;

    bf16x8 kf[2][4];
    float4 kr[16];

    auto KISSUE = [&](int cc) {
        #pragma unroll
        for (int ct = 0; ct < 2; ++ct) {
            const float* kp = &kc[(((size_t)b * MAXS_ + cc * 32 + ct * 16 + li) * H_ + h) * HD_ + lg * 8];
            #pragma unroll
            for (int kk = 0; kk < 4; ++kk) {
                kr[ct * 8 + 2 * kk]     = *(const float4*)(kp + kk * 32);
                kr[ct * 8 + 2 * kk + 1] = *(const float4*)(kp + kk * 32 + 4);
            }
        }
    };
    auto VSTAGE = [&](int cc) {
        const float* src = vc + (((size_t)b * MAXS_ + cc * 32) * H_ + h) * HD_;
        #pragma unroll
        for (int i = 0; i < 16; ++i) {
            GLD16(src + (size_t)(2 * i + (lane >> 5)) * (H_ * HD_) + (lane & 31) * 4,
                  VLDSw + i * 1024);
        }
    };
    auto KBUILD = [&]() {
        #pragma unroll
        for (int ct = 0; ct < 2; ++ct)
            #pragma unroll
            for (int kk = 0; kk < 4; ++kk) {
                bf16x8 f;
                f[0] = f2b(kr[ct * 8 + 2 * kk].x); f[1] = f2b(kr[ct * 8 + 2 * kk].y);
                f[2] = f2b(kr[ct * 8 + 2 * kk].z); f[3] = f2b(kr[ct * 8 + 2 * kk].w);
                f[4] = f2b(kr[ct * 8 + 2 * kk + 1].x); f[5] = f2b(kr[ct * 8 + 2 * kk + 1].y);
                f[6] = f2b(kr[ct * 8 + 2 * kk + 1].z); f[7] = f2b(kr[ct * 8 + 2 * kk + 1].w);
                kf[ct][kk] = f;
            }
    };

    auto COMPUTE = [&](int s0, bool deep) {
        f32x4 sc[2][2];
        #pragma unroll
        for (int ct = 0; ct < 2; ++ct)
            #pragma unroll
            for (int rt = 0; rt < 2; ++rt) {
                f32x4 acc;
                for (int r = 0; r < 4; ++r) acc[r] = 0.f;
                #pragma unroll
                for (int kk = 0; kk < 4; ++kk)
                    acc = __builtin_amdgcn_mfma_f32_16x16x32_bf16(kf[ct][kk], qf[rt][kk], acc, 0, 0, 0);
                sc[ct][rt] = acc;
            }
        float corr[2];
        #pragma unroll
        for (int rt = 0; rt < 2; ++rt) {
            float xv[8];
            #pragma unroll
            for (int ct = 0; ct < 2; ++ct)
                #pragma unroll
                for (int r = 0; r < 4; ++r) {
                    float xx = sc[ct][rt][r] * scale;
                    if (s0 + ct * 16 + 4 * lg + r >= L) xx = -1e30f;
                    xv[ct * 4 + r] = xx;
                }
            float mx = fmaxf(fmaxf(fmaxf(xv[0], xv[1]), fmaxf(xv[2], xv[3])),
                             fmaxf(fmaxf(xv[4], xv[5]), fmaxf(xv[6], xv[7])));
            mx = fmaxf(mx, __shfl_xor(mx, 16, 64));
            mx = fmaxf(mx, __shfl_xor(mx, 32, 64));
            float mnew = fmaxf(m_r[rt], mx);
            corr[rt] = __expf(m_r[rt] - mnew);
            float p[8], ssum = 0.f;
            #pragma unroll
            for (int j = 0; j < 8; ++j) { p[j] = __expf(xv[j] - mnew); ssum += p[j]; }
            ssum += __shfl_xor(ssum, 16, 64);
            ssum += __shfl_xor(ssum, 32, 64);
            l_r[rt] = l_r[rt] * corr[rt] + ssum;
            m_r[rt] = mnew;
            #pragma unroll
            for (int ct = 0; ct < 2; ++ct)
                #pragma unroll
                for (int r = 0; r < 4; ++r)
                    Plds[wave][rt * 16 + li][ct * 16 + 4 * lg + r] = __float2bfloat16(p[ct * 4 + r]);
        }
        #pragma unroll
        for (int rt = 0; rt < 2; ++rt) {
            float cq[4];
            #pragma unroll
            for (int r = 0; r < 4; ++r) cq[r] = __shfl(corr[rt], 20 * lg + r, 64);
            #pragma unroll
            for (int ht = 0; ht < 8; ++ht)
                #pragma unroll
                for (int r = 0; r < 4; ++r) o[rt][ht][r] *= cq[r];
        }
        if (deep) asm volatile("s_waitcnt vmcnt(16) lgkmcnt(0)" ::: "memory");
        else      asm volatile("s_waitcnt vmcnt(0) lgkmcnt(0)" ::: "memory");
        __builtin_amdgcn_sched_barrier(0);
        bf16x8 pf[2];
        pf[0] = *(const bf16x8*)(&Plds[wave][li][lg * 8]);
        pf[1] = *(const bf16x8*)(&Plds[wave][16 + li][lg * 8]);
        #pragma unroll
        for (int ht = 0; ht < 8; ++ht) {
            bf16x8 vf;
            #pragma unroll
            for (int j = 0; j < 8; ++j)
                vf[j] = f2b(Vf[lg * 8 + j][ht * 16 + li]);
            #pragma unroll
            for (int rt = 0; rt < 2; ++rt)
                o[rt][ht] = __builtin_amdgcn_mfma_f32_16x16x32_bf16(pf[rt], vf, o[rt][ht], 0, 0, 0);
        }
    };

    int c = wave;
    if (c < ccache) {
        KISSUE(c);
        VSTAGE(c);
        for (;;) {
            const int s0 = c * 32;
            const int nc = c + 4;
            const bool more = nc < ccache;
            KBUILD();
            if (more) KISSUE(nc);
            COMPUTE(s0, more);
            asm volatile("s_waitcnt lgkmcnt(0)" ::: "memory");
            if (more) VSTAGE(nc);
            c = nc;
            if (!more) break;
        }
    }
    for (; c < nch; c += 4) {
        const int s0 = c * 32;
        #pragma unroll
        for (int u = 0; u < 16; ++u) {
            int F = lane + 64 * u;
            int s = F >> 5, q = F & 31;
            int ss = s0 + s;
            float4 v;
            if (ss < sp) {
                v = *(const float4*)&vc[(((size_t)b * MAXS_ + ss) * H_ + h) * HD_ + q * 4];
            } else if (ss < L) {
                ushort4 uu = *(const ushort4*)&vb[(((size_t)b * T_ + (ss - sp)) * H_ + h) * HD_ + q * 4];
                v = make_float4(b2f((short)uu.x), b2f((short)uu.y), b2f((short)uu.z), b2f((short)uu.w));
            } else {
                v = make_float4(0.f, 0.f, 0.f, 0.f);
            }
            *(float4*)&Vf[s][q * 4] = v;
        }
        #pragma unroll
        for (int ct = 0; ct < 2; ++ct) {
            int s = s0 + ct * 16 + li;
            if (s < sp) {
                const float* kp = &kc[(((size_t)b * MAXS_ + s) * H_ + h) * HD_];
                #pragma unroll
                for (int kk = 0; kk < 4; ++kk) {
                    float4 v0 = *(const float4*)(&kp[kk * 32 + lg * 8]);
                    float4 v1 = *(const float4*)(&kp[kk * 32 + lg * 8 + 4]);
                    bf16x8 f;
                    f[0] = f2b(v0.x); f[1] = f2b(v0.y); f[2] = f2b(v0.z); f[3] = f2b(v0.w);
                    f[4] = f2b(v1.x); f[5] = f2b(v1.y); f[6] = f2b(v1.z); f[7] = f2b(v1.w);
                    kf[ct][kk] = f;
                }
            } else if (s < L) {
                const bf16* kp = &kb[((size_t)(b * T_ + s - sp) * H_ + h) * HD_];
                #pragma unroll
                for (int kk = 0; kk < 4; ++kk)
                    kf[ct][kk] = *(const bf16x8*)(kp + kk * 32 + lg * 8);
            } else {
                #pragma unroll
                for (int kk = 0; kk < 4; ++kk) {
                    bf16x8 f;
                    #pragma unroll
                    for (int j = 0; j < 8; ++j) f[j] = 0;
                    kf[ct][kk] = f;
                }
            }
        }
        COMPUTE(s0, false);
    }

    // ---- cross-wave combine ----
    if (lg == 0) {
        #pragma unroll
        for (int rt = 0; rt < 2; ++rt) {
            msh[wave][rt * 16 + li] = m_r[rt];
            lsh[wave][rt * 16 + li] = l_r[rt];
        }
    }
    __syncthreads();
    float corr2[2][4];
    #pragma unroll
    for (int rt = 0; rt < 2; ++rt)
        for (int r = 0; r < 4; ++r) {
            int row = rt * 16 + lg * 4 + r;
            float M = fmaxf(fmaxf(msh[0][row], msh[1][row]), fmaxf(msh[2][row], msh[3][row]));
            corr2[rt][r] = __expf(msh[wave][row] - M);
        }
    if (tid < 32) {
        int row = tid;
        float M = fmaxf(fmaxf(msh[0][row], msh[1][row]), fmaxf(msh[2][row], msh[3][row]));
        float lt = 0.f;
        #pragma unroll
        for (int w = 0; w < 4; ++w) lt += lsh[w][row] * __expf(msh[w][row] - M);
        ltot[row] = lt;
    }
    __syncthreads();
    for (int w = 0; w < 4; ++w) {
        if (wave == w) {
            #pragma unroll
            for (int rt = 0; rt < 2; ++rt)
                for (int ht = 0; ht < 8; ++ht)
                    for (int r = 0; r < 4; ++r) {
                        int row = rt * 16 + lg * 4 + r, col = ht * 16 + li;
                        float val = o[rt][ht][r] * corr2[rt][r];
                        if (w == 0) Osh[row][col] = val;
                        else Osh[row][col] += val;
                    }
        }
        __syncthreads();
    }
    {
        int row = tid >> 3;
        int c0 = (tid & 7) * 16;
        float inv = 1.0f / ltot[row];
        #pragma unroll
        for (int j = 0; j < 16; ++j)
            ob[(size_t)(b * T_ + row) * D_ + h * HD_ + c0 + j] = __float2bfloat16(Osh[row][c0 + j] * inv);
    }
}

extern "C" void kernel_launch(void* const* d_in, const int* in_sizes, int n_in,
                              void* d_out, int out_size, void* d_ws, size_t ws_size,
                              hipStream_t stream) {
    const float* x  = (const float*)d_in[0];
    const float* wq = (const float*)d_in[1];
    const float* wk = (const float*)d_in[2];
    const float* wv = (const float*)d_in[3];
    const float* wo = (const float*)d_in[4];
    const float* kc = (const float*)d_in[5];
    const float* vc = (const float*)d_in[6];
    const int*   sp = (const int*)d_in[7];

    char* ws = (char*)d_ws;
    const size_t MT = (size_t)M_ * D_;                 // 2M elements
    bf16* xb = (bf16*)ws;
    bf16* qb = xb + MT;
    bf16* kb = qb + MT;
    bf16* vb = kb + MT;
    bf16* ab = vb + MT;

    conv_x<<<dim3((int)(MT / 8 / 256)), 256, 0, stream>>>(x, xb);
    gemm_qkvw<<<dim3(96, 8), 256, 0, stream>>>(xb, wq, wk, wv, qb);
    rope_inplace<<<dim3((int)(MT / 8 / 256)), 256, 0, stream>>>(qb, kb);
    attn<<<dim3(B_ * H_), 256, 0, stream>>>(qb, kb, vb, kc, vc, sp, ab);
    gemm_wof<<<dim3(64, 8), 256, 0, stream>>>(ab, wo, (float*)d_out);
}

// Round 19
// 300.428 us; speedup vs baseline: 1.4120x; 1.0128x over previous
//
#include <hip/hip_runtime.h>
#include <hip/hip_bf16.h>

#define B_ 16
#define T_ 32
#define D_ 4096
#define H_ 32
#define HD_ 128
#define MAXS_ 2048
#define M_ (B_*T_)   // 512 rows

typedef __hip_bfloat16 bf16;
typedef __attribute__((ext_vector_type(8))) short bf16x8;
typedef __attribute__((ext_vector_type(4))) float f32x4;

static __device__ __forceinline__ short f2b(float f) {
    bf16 h = __float2bfloat16(f);
    return *reinterpret_cast<short*>(&h);
}
static __device__ __forceinline__ float b2f(short s) {
    bf16 h;
    *reinterpret_cast<short*>(&h) = s;
    return __bfloat162float(h);
}

// async global->LDS, 16B per lane; LDS dest is wave-uniform base + lane*16
#define GLD16(gsrc, ldst) \
    __builtin_amdgcn_global_load_lds((const __attribute__((address_space(1))) void*)(gsrc), \
        (__attribute__((address_space(3))) void*)(ldst), 16, 0, 0)

// ---------------- x f32 -> bf16 ----------------
__global__ __launch_bounds__(256) void conv_x(const float* __restrict__ x, bf16* __restrict__ xb) {
    int idx = blockIdx.x * 256 + threadIdx.x;   // 8-element unit
    const float4* xf = (const float4*)x;
    float4 a = xf[idx * 2], b = xf[idx * 2 + 1];
    bf16x8 o;
    o[0] = f2b(a.x); o[1] = f2b(a.y); o[2] = f2b(a.z); o[3] = f2b(a.w);
    o[4] = f2b(b.x); o[5] = f2b(b.y); o[6] = f2b(b.z); o[7] = f2b(b.w);
    *(bf16x8*)&xb[(size_t)idx * 8] = o;
}

// ---------------- QKV GEMM, fused weight transpose+convert + fused RoPE epilogue ----------------
// BK=64 (2x 32-k halves). Grid (96, 8): blockIdx.x>>5 selects wq/wk/wv.
// q,k (wsel<2) are roped in the f32 epilogue (pair via shfl_xor(1)) before bf16 store.
__global__ __launch_bounds__(256) void gemm_qkvw(const bf16* __restrict__ A,
        const float* __restrict__ wq, const float* __restrict__ wk,
        const float* __restrict__ wv, bf16* __restrict__ out) {
    const int K = D_;
    const int wsel = blockIdx.x >> 5;
    const float* W = (wsel == 0) ? wq : (wsel == 1) ? wk : wv;
    const int lcol0 = (blockIdx.x & 31) * 128;
    bf16* Ob = out + (size_t)wsel * M_ * D_;
    __shared__ bf16 As[2][64 * 32];
    __shared__ short Bs[2][128][40];
    const int tid = threadIdx.x, lane = tid & 63, wave = tid >> 6;
    const int wr = wave >> 1, wc = wave & 1;
    const int lg = lane >> 4, li = lane & 15;
    const int row0 = blockIdx.y * 64;
    const int bq = tid & 31, kq = tid >> 5;
    f32x4 acc[2][4];
    #pragma unroll
    for (int i = 0; i < 2; ++i)
        #pragma unroll
        for (int j = 0; j < 4; ++j)
            #pragma unroll
            for (int r = 0; r < 4; ++r) acc[i][j][r] = 0.f;

    const int sw = (li & 3) << 4;
    for (int k0 = 0; k0 < K; k0 += 64) {
        float4 wv4[2][4];
        #pragma unroll
        for (int h = 0; h < 2; ++h)
            #pragma unroll
            for (int i = 0; i < 4; ++i)
                wv4[h][i] = *(const float4*)&W[(size_t)(k0 + 32 * h + kq * 4 + i) * D_ + lcol0 + bq * 4];
        {
            int X = tid * 16;
            int row = X >> 6;
            int kb = (X & 63) ^ ((row & 3) << 4);
            GLD16(A + (size_t)(row0 + row) * K + k0 + (kb >> 1),      (char*)As[0] + wave * 1024);
            GLD16(A + (size_t)(row0 + row) * K + k0 + 32 + (kb >> 1), (char*)As[1] + wave * 1024);
        }
        #pragma unroll
        for (int h = 0; h < 2; ++h)
            #pragma unroll
            for (int j = 0; j < 4; ++j) {
                int n = bq * 4 + j;
                short4 col;
                col.x = f2b(((const float*)&wv4[h][0])[j]);
                col.y = f2b(((const float*)&wv4[h][1])[j]);
                col.z = f2b(((const float*)&wv4[h][2])[j]);
                col.w = f2b(((const float*)&wv4[h][3])[j]);
                *(short4*)((char*)&Bs[h][n][0] + ((kq * 8) ^ (((n >> 4) & 3) << 4))) = col;
            }
        __syncthreads();
        bf16x8 af[2][2], bfr[2][4];
        #pragma unroll
        for (int h = 0; h < 2; ++h) {
            #pragma unroll
            for (int i = 0; i < 2; ++i) {
                int row = wr * 32 + i * 16 + li;
                af[h][i] = *(const bf16x8*)((const char*)As[h] + row * 64 + ((lg * 16) ^ sw));
            }
            #pragma unroll
            for (int j = 0; j < 4; ++j) {
                int row = wc * 64 + j * 16 + li;
                bfr[h][j] = *(const bf16x8*)((const char*)&Bs[h][row][0] + ((lg * 16) ^ (((row >> 4) & 3) << 4)));
            }
        }
        #pragma unroll
        for (int h = 0; h < 2; ++h)
            #pragma unroll
            for (int i = 0; i < 2; ++i)
                #pragma unroll
                for (int j = 0; j < 4; ++j)
                    acc[i][j] = __builtin_amdgcn_mfma_f32_16x16x32_bf16(af[h][i], bfr[h][j], acc[i][j], 0, 0, 0);
        __syncthreads();
    }
    if (wsel < 2) {
        // RoPE epilogue: pair (2p,2p+1) lives in lanes (li, li^1); same c,s for both.
        #pragma unroll
        for (int i = 0; i < 2; ++i)
            #pragma unroll
            for (int j = 0; j < 4; ++j) {
                int hd = wc * 64 + j * 16 + li;            // lcol0 is a multiple of 128
                float theta = exp2f(-(float)(hd >> 1) * 0.41524101186092787f);  // log2(10000)/32
                #pragma unroll
                for (int r = 0; r < 4; ++r) {
                    float v = acc[i][j][r];
                    float pv = __shfl_xor(v, 1, 64);
                    int row = row0 + wr * 32 + i * 16 + lg * 4 + r;
                    int t = row & 31;
                    float s, cc;
                    sincosf((float)t * theta, &s, &cc);
                    float outv = (li & 1) ? (v * cc + pv * s) : (v * cc - pv * s);
                    int col = lcol0 + wc * 64 + j * 16 + li;
                    Ob[(size_t)row * D_ + col] = __float2bfloat16(outv);
                }
            }
    } else {
        #pragma unroll
        for (int i = 0; i < 2; ++i)
            for (int j = 0; j < 4; ++j)
                for (int r = 0; r < 4; ++r) {
                    int row = row0 + wr * 32 + i * 16 + lg * 4 + r;
                    int col = lcol0 + wc * 64 + j * 16 + li;
                    Ob[(size_t)row * D_ + col] = __float2bfloat16(acc[i][j][r]);
                }
    }
}

// ---------------- wo GEMM, fused weight transpose+convert, BK=64, BN=64, f32 out ----------------
__global__ __launch_bounds__(256) void gemm_wof(const bf16* __restrict__ A,
        const float* __restrict__ W, float* __restrict__ O) {
    const int K = D_;
    const int lcol0 = blockIdx.x * 64;
    __shared__ bf16 As[2][64 * 32];
    __shared__ short Bs[2][64][40];
    const int tid = threadIdx.x, lane = tid & 63, wave = tid >> 6;
    const int wr = wave >> 1, wc = wave & 1;
    const int lg = lane >> 4, li = lane & 15;
    const int row0 = blockIdx.y * 64;
    const int bq = tid & 15, kq = tid >> 4;   // staging unit: 4k x 4n, kq 0..15 covers 64k
    f32x4 acc[2][2];
    #pragma unroll
    for (int i = 0; i < 2; ++i)
        #pragma unroll
        for (int j = 0; j < 2; ++j)
            #pragma unroll
            for (int r = 0; r < 4; ++r) acc[i][j][r] = 0.f;

    const int sw = (li & 3) << 4;
    for (int k0 = 0; k0 < K; k0 += 64) {
        float4 wv4[4];
        #pragma unroll
        for (int i = 0; i < 4; ++i)
            wv4[i] = *(const float4*)&W[(size_t)(k0 + kq * 4 + i) * D_ + lcol0 + bq * 4];
        {
            int X = tid * 16;
            int row = X >> 6;
            int kb = (X & 63) ^ ((row & 3) << 4);
            GLD16(A + (size_t)(row0 + row) * K + k0 + (kb >> 1),      (char*)As[0] + wave * 1024);
            GLD16(A + (size_t)(row0 + row) * K + k0 + 32 + (kb >> 1), (char*)As[1] + wave * 1024);
        }
        const int h = kq >> 3, kl = kq & 7;
        #pragma unroll
        for (int j = 0; j < 4; ++j) {
            int n = bq * 4 + j;
            short4 col;
            col.x = f2b(((const float*)&wv4[0])[j]);
            col.y = f2b(((const float*)&wv4[1])[j]);
            col.z = f2b(((const float*)&wv4[2])[j]);
            col.w = f2b(((const float*)&wv4[3])[j]);
            *(short4*)((char*)&Bs[h][n][0] + ((kl * 8) ^ (((n >> 4) & 3) << 4))) = col;
        }
        __syncthreads();
        bf16x8 af[2][2], bfr[2][2];
        #pragma unroll
        for (int h2 = 0; h2 < 2; ++h2) {
            #pragma unroll
            for (int i = 0; i < 2; ++i) {
                int row = wr * 32 + i * 16 + li;
                af[h2][i] = *(const bf16x8*)((const char*)As[h2] + row * 64 + ((lg * 16) ^ sw));
            }
            #pragma unroll
            for (int j = 0; j < 2; ++j) {
                int row = wc * 32 + j * 16 + li;
                bfr[h2][j] = *(const bf16x8*)((const char*)&Bs[h2][row][0] + ((lg * 16) ^ (((row >> 4) & 3) << 4)));
            }
        }
        #pragma unroll
        for (int h2 = 0; h2 < 2; ++h2)
            #pragma unroll
            for (int i = 0; i < 2; ++i)
                #pragma unroll
                for (int j = 0; j < 2; ++j)
                    acc[i][j] = __builtin_amdgcn_mfma_f32_16x16x32_bf16(af[h2][i], bfr[h2][j], acc[i][j], 0, 0, 0);
        __syncthreads();
    }
    #pragma unroll
    for (int i = 0; i < 2; ++i)
        for (int j = 0; j < 2; ++j)
            for (int r = 0; r < 4; ++r) {
                int row = row0 + wr * 32 + i * 16 + lg * 4 + r;
                int col = lcol0 + wc * 32 + j * 16 + li;
                O[(size_t)row * D_ + col] = acc[i][j][r];
            }
}

// ---------------- Fused flash attention: deep async staging (gload_lds V + reg-prefetch K) ----------------
__global__ __launch_bounds__(256, 2) void attn(const bf16* __restrict__ qb,
        const bf16* __restrict__ kb, const bf16* __restrict__ vb,
        const float* __restrict__ kc, const float* __restrict__ vc,
        const int* __restrict__ spp, bf16* __restrict__ ob) {
    const int bh = blockIdx.x;
    const int b = bh >> 5, h = bh & 31;
    const int sp = *spp;
    const int L = sp + T_;
    const int tid = threadIdx.x, lane = tid & 63, wave = tid >> 6;
    const int lg = lane >> 4, li = lane & 15;

    __shared__ __align__(16) char smem[76928];
    char* VLDSw = smem + wave * 16384;
    float(*Vf)[128] = (float(*)[128])VLDSw;
    auto Plds = (bf16(*)[32][40])(smem + 65536);
    auto msh  = (float(*)[32])(smem + 75776);
    auto lsh  = (float(*)[32])(smem + 76288);
    float* ltot = (float*)(smem + 76800);
    float(*Osh)[128] = (float(*)[128])smem;            // post-loop overlay

    bf16x8 qf[2][4];
    #pragma unroll
    for (int rt = 0; rt < 2; ++rt)
        #pragma unroll
        for (int kk = 0; kk < 4; ++kk)
            qf[rt][kk] = *(const bf16x8*)(&qb[((size_t)(b * T_ + rt * 16 + li) * H_ + h) * HD_ + kk * 32 + lg * 8]);

    f32x4 o[2][8];
    float m_r[2], l_r[2];
    m_r[0] = m_r[1] = -1e30f;
    l_r[0] = l_r[1] = 0.f;
    #pragma unroll
    for (int rt = 0; rt < 2; ++rt) for (int ht = 0; ht < 8; ++ht) for (int r = 0; r < 4; ++r) o[rt][ht][r] = 0.f;

    const float scale = 0.08838834764831845f;  // 1/sqrt(128)
    const int nch = (L + 31) >> 5;
    const int ccache = sp >> 5;

    bf16x8 kf[2][4];
    float4 kr[16];

    auto KISSUE = [&](int cc) {
        #pragma unroll
        for (int ct = 0; ct < 2; ++ct) {
            const float* kp = &kc[(((size_t)b * MAXS_ + cc * 32 + ct * 16 + li) * H_ + h) * HD_ + lg * 8];
            #pragma unroll
            for (int kk = 0; kk < 4; ++kk) {
                kr[ct * 8 + 2 * kk]     = *(const float4*)(kp + kk * 32);
                kr[ct * 8 + 2 * kk + 1] = *(const float4*)(kp + kk * 32 + 4);
            }
        }
    };
    auto VSTAGE = [&](int cc) {
        const float* src = vc + (((size_t)b * MAXS_ + cc * 32) * H_ + h) * HD_;
        #pragma unroll
        for (int i = 0; i < 16; ++i) {
            GLD16(src + (size_t)(2 * i + (lane >> 5)) * (H_ * HD_) + (lane & 31) * 4,
                  VLDSw + i * 1024);
        }
    };
    auto KBUILD = [&]() {
        #pragma unroll
        for (int ct = 0; ct < 2; ++ct)
            #pragma unroll
            for (int kk = 0; kk < 4; ++kk) {
                bf16x8 f;
                f[0] = f2b(kr[ct * 8 + 2 * kk].x); f[1] = f2b(kr[ct * 8 + 2 * kk].y);
                f[2] = f2b(kr[ct * 8 + 2 * kk].z); f[3] = f2b(kr[ct * 8 + 2 * kk].w);
                f[4] = f2b(kr[ct * 8 + 2 * kk + 1].x); f[5] = f2b(kr[ct * 8 + 2 * kk + 1].y);
                f[6] = f2b(kr[ct * 8 + 2 * kk + 1].z); f[7] = f2b(kr[ct * 8 + 2 * kk + 1].w);
                kf[ct][kk] = f;
            }
    };

    auto COMPUTE = [&](int s0, bool deep) {
        f32x4 sc[2][2];
        #pragma unroll
        for (int ct = 0; ct < 2; ++ct)
            #pragma unroll
            for (int rt = 0; rt < 2; ++rt) {
                f32x4 acc;
                for (int r = 0; r < 4; ++r) acc[r] = 0.f;
                #pragma unroll
                for (int kk = 0; kk < 4; ++kk)
                    acc = __builtin_amdgcn_mfma_f32_16x16x32_bf16(kf[ct][kk], qf[rt][kk], acc, 0, 0, 0);
                sc[ct][rt] = acc;
            }
        float corr[2];
        #pragma unroll
        for (int rt = 0; rt < 2; ++rt) {
            float xv[8];
            #pragma unroll
            for (int ct = 0; ct < 2; ++ct)
                #pragma unroll
                for (int r = 0; r < 4; ++r) {
                    float xx = sc[ct][rt][r] * scale;
                    if (s0 + ct * 16 + 4 * lg + r >= L) xx = -1e30f;
                    xv[ct * 4 + r] = xx;
                }
            float mx = fmaxf(fmaxf(fmaxf(xv[0], xv[1]), fmaxf(xv[2], xv[3])),
                             fmaxf(fmaxf(xv[4], xv[5]), fmaxf(xv[6], xv[7])));
            mx = fmaxf(mx, __shfl_xor(mx, 16, 64));
            mx = fmaxf(mx, __shfl_xor(mx, 32, 64));
            float mnew = fmaxf(m_r[rt], mx);
            corr[rt] = __expf(m_r[rt] - mnew);
            float p[8], ssum = 0.f;
            #pragma unroll
            for (int j = 0; j < 8; ++j) { p[j] = __expf(xv[j] - mnew); ssum += p[j]; }
            ssum += __shfl_xor(ssum, 16, 64);
            ssum += __shfl_xor(ssum, 32, 64);
            l_r[rt] = l_r[rt] * corr[rt] + ssum;
            m_r[rt] = mnew;
            #pragma unroll
            for (int ct = 0; ct < 2; ++ct)
                #pragma unroll
                for (int r = 0; r < 4; ++r)
                    Plds[wave][rt * 16 + li][ct * 16 + 4 * lg + r] = __float2bfloat16(p[ct * 4 + r]);
        }
        #pragma unroll
        for (int rt = 0; rt < 2; ++rt) {
            float cq[4];
            #pragma unroll
            for (int r = 0; r < 4; ++r) cq[r] = __shfl(corr[rt], 20 * lg + r, 64);
            #pragma unroll
            for (int ht = 0; ht < 8; ++ht)
                #pragma unroll
                for (int r = 0; r < 4; ++r) o[rt][ht][r] *= cq[r];
        }
        if (deep) asm volatile("s_waitcnt vmcnt(16) lgkmcnt(0)" ::: "memory");
        else      asm volatile("s_waitcnt vmcnt(0) lgkmcnt(0)" ::: "memory");
        __builtin_amdgcn_sched_barrier(0);
        bf16x8 pf[2];
        pf[0] = *(const bf16x8*)(&Plds[wave][li][lg * 8]);
        pf[1] = *(const bf16x8*)(&Plds[wave][16 + li][lg * 8]);
        #pragma unroll
        for (int ht = 0; ht < 8; ++ht) {
            bf16x8 vf;
            #pragma unroll
            for (int j = 0; j < 8; ++j)
                vf[j] = f2b(Vf[lg * 8 + j][ht * 16 + li]);
            #pragma unroll
            for (int rt = 0; rt < 2; ++rt)
                o[rt][ht] = __builtin_amdgcn_mfma_f32_16x16x32_bf16(pf[rt], vf, o[rt][ht], 0, 0, 0);
        }
    };

    int c = wave;
    if (c < ccache) {
        KISSUE(c);
        VSTAGE(c);
        for (;;) {
            const int s0 = c * 32;
            const int nc = c + 4;
            const bool more = nc < ccache;
            KBUILD();
            if (more) KISSUE(nc);
            COMPUTE(s0, more);
            asm volatile("s_waitcnt lgkmcnt(0)" ::: "memory");
            if (more) VSTAGE(nc);
            c = nc;
            if (!more) break;
        }
    }
    for (; c < nch; c += 4) {
        const int s0 = c * 32;
        #pragma unroll
        for (int u = 0; u < 16; ++u) {
            int F = lane + 64 * u;
            int s = F >> 5, q = F & 31;
            int ss = s0 + s;
            float4 v;
            if (ss < sp) {
                v = *(const float4*)&vc[(((size_t)b * MAXS_ + ss) * H_ + h) * HD_ + q * 4];
            } else if (ss < L) {
                ushort4 uu = *(const ushort4*)&vb[(((size_t)b * T_ + (ss - sp)) * H_ + h) * HD_ + q * 4];
                v = make_float4(b2f((short)uu.x), b2f((short)uu.y), b2f((short)uu.z), b2f((short)uu.w));
            } else {
                v = make_float4(0.f, 0.f, 0.f, 0.f);
            }
            *(float4*)&Vf[s][q * 4] = v;
        }
        #pragma unroll
        for (int ct = 0; ct < 2; ++ct) {
            int s = s0 + ct * 16 + li;
            if (s < sp) {
                const float* kp = &kc[(((size_t)b * MAXS_ + s) * H_ + h) * HD_];
                #pragma unroll
                for (int kk = 0; kk < 4; ++kk) {
                    float4 v0 = *(const float4*)(&kp[kk * 32 + lg * 8]);
                    float4 v1 = *(const float4*)(&kp[kk * 32 + lg * 8 + 4]);
                    bf16x8 f;
                    f[0] = f2b(v0.x); f[1] = f2b(v0.y); f[2] = f2b(v0.z); f[3] = f2b(v0.w);
                    f[4] = f2b(v1.x); f[5] = f2b(v1.y); f[6] = f2b(v1.z); f[7] = f2b(v1.w);
                    kf[ct][kk] = f;
                }
            } else if (s < L) {
                const bf16* kp = &kb[((size_t)(b * T_ + s - sp) * H_ + h) * HD_];
                #pragma unroll
                for (int kk = 0; kk < 4; ++kk)
                    kf[ct][kk] = *(const bf16x8*)(kp + kk * 32 + lg * 8);
            } else {
                #pragma unroll
                for (int kk = 0; kk < 4; ++kk) {
                    bf16x8 f;
                    #pragma unroll
                    for (int j = 0; j < 8; ++j) f[j] = 0;
                    kf[ct][kk] = f;
                }
            }
        }
        COMPUTE(s0, false);
    }

    // ---- cross-wave combine ----
    if (lg == 0) {
        #pragma unroll
        for (int rt = 0; rt < 2; ++rt) {
            msh[wave][rt * 16 + li] = m_r[rt];
            lsh[wave][rt * 16 + li] = l_r[rt];
        }
    }
    __syncthreads();
    float corr2[2][4];
    #pragma unroll
    for (int rt = 0; rt < 2; ++rt)
        for (int r = 0; r < 4; ++r) {
            int row = rt * 16 + lg * 4 + r;
            float M = fmaxf(fmaxf(msh[0][row], msh[1][row]), fmaxf(msh[2][row], msh[3][row]));
            corr2[rt][r] = __expf(msh[wave][row] - M);
        }
    if (tid < 32) {
        int row = tid;
        float M = fmaxf(fmaxf(msh[0][row], msh[1][row]), fmaxf(msh[2][row], msh[3][row]));
        float lt = 0.f;
        #pragma unroll
        for (int w = 0; w < 4; ++w) lt += lsh[w][row] * __expf(msh[w][row] - M);
        ltot[row] = lt;
    }
    __syncthreads();
    for (int w = 0; w < 4; ++w) {
        if (wave == w) {
            #pragma unroll
            for (int rt = 0; rt < 2; ++rt)
                for (int ht = 0; ht < 8; ++ht)
                    for (int r = 0; r < 4; ++r) {
                        int row = rt * 16 + lg * 4 + r, col = ht * 16 + li;
                        float val = o[rt][ht][r] * corr2[rt][r];
                        if (w == 0) Osh[row][col] = val;
                        else Osh[row][col] += val;
                    }
        }
        __syncthreads();
    }
    {
        int row = tid >> 3;
        int c0 = (tid & 7) * 16;
        float inv = 1.0f / ltot[row];
        #pragma unroll
        for (int j = 0; j < 16; ++j)
            ob[(size_t)(b * T_ + row) * D_ + h * HD_ + c0 + j] = __float2bfloat16(Osh[row][c0 + j] * inv);
    }
}

extern "C" void kernel_launch(void* const* d_in, const int* in_sizes, int n_in,
                              void* d_out, int out_size, void* d_ws, size_t ws_size,
                              hipStream_t stream) {
    const float* x  = (const float*)d_in[0];
    const float* wq = (const float*)d_in[1];
    const float* wk = (const float*)d_in[2];
    const float* wv = (const float*)d_in[3];
    const float* wo = (const float*)d_in[4];
    const float* kc = (const float*)d_in[5];
    const float* vc = (const float*)d_in[6];
    const int*   sp = (const int*)d_in[7];

    char* ws = (char*)d_ws;
    const size_t MT = (size_t)M_ * D_;                 // 2M elements
    bf16* xb = (bf16*)ws;
    bf16* qb = xb + MT;
    bf16* kb = qb + MT;
    bf16* vb = kb + MT;
    bf16* ab = vb + MT;

    conv_x<<<dim3((int)(MT / 8 / 256)), 256, 0, stream>>>(x, xb);
    gemm_qkvw<<<dim3(96, 8), 256, 0, stream>>>(xb, wq, wk, wv, qb);
    attn<<<dim3(B_ * H_), 256, 0, stream>>>(qb, kb, vb, kc, vc, sp, ab);
    gemm_wof<<<dim3(64, 8), 256, 0, stream>>>(ab, wo, (float*)d_out);
}